// Round 2
// baseline (3226.251 us; speedup 1.0000x reference)
//
#include <hip/hip_runtime.h>
#include <math.h>

#define N_NODES 50000
#define FEAT    256
#define EDGES   200000
#define HEADS   4
#define CH      128
#define HID     512   // HEADS*CH
#define NGRAPH  256
#define NCLS    10

// ---------------------------------------------------------------------------
// Tiled fp32 GEMM: C[M,Nc] = A[M,K] @ B[K,Nc] + bias, with explicit leading
// dims so we can write head-slices (B = W + h*CH, ldb=512, ldc=128).
// BM=BN=64, BK=16, 256 threads, 4x4 micro-tile per thread.
// ---------------------------------------------------------------------------
#define BM 64
#define BN 64
#define BK 16

__device__ __forceinline__ void gemm_body(
    const float* __restrict__ A, int lda,
    const float* __restrict__ B, int ldb,
    const float* __restrict__ bias,
    float* __restrict__ Cmat, int ldc,
    int M, int K, int rowBase, int colBase) {
  __shared__ float As[BK][BM + 1];
  __shared__ float Bs[BK][BN];
  int tid = threadIdx.x;
  int tx = tid & 15, ty = tid >> 4;
  float c[4][4] = {};
  for (int k0 = 0; k0 < K; k0 += BK) {
#pragma unroll
    for (int l = 0; l < 4; ++l) {
      int idx = tid + l * 256;
      int r = idx >> 4, kk = idx & 15;
      int row = rowBase + r;
      As[kk][r] = (row < M) ? A[(size_t)row * lda + k0 + kk] : 0.f;
    }
#pragma unroll
    for (int l = 0; l < 4; ++l) {
      int idx = tid + l * 256;
      int kk = idx >> 6, cc = idx & 63;
      Bs[kk][cc] = B[(size_t)(k0 + kk) * ldb + colBase + cc];
    }
    __syncthreads();
#pragma unroll
    for (int kk = 0; kk < BK; ++kk) {
      float a[4], b[4];
#pragma unroll
      for (int i = 0; i < 4; ++i) a[i] = As[kk][ty + 16 * i];
#pragma unroll
      for (int j = 0; j < 4; ++j) b[j] = Bs[kk][tx + 16 * j];
#pragma unroll
      for (int i = 0; i < 4; ++i)
#pragma unroll
        for (int j = 0; j < 4; ++j) c[i][j] += a[i] * b[j];
    }
    __syncthreads();
  }
#pragma unroll
  for (int i = 0; i < 4; ++i) {
    int row = rowBase + ty + 16 * i;
    if (row >= M) continue;
#pragma unroll
    for (int j = 0; j < 4; ++j) {
      int col = colBase + tx + 16 * j;
      Cmat[(size_t)row * ldc + col] = c[i][j] + bias[col];
    }
  }
}

__global__ __launch_bounds__(256) void gemm_bias(
    const float* __restrict__ A, int lda,
    const float* __restrict__ B, int ldb,
    const float* __restrict__ bias,
    float* __restrict__ Cmat, int ldc,
    int M, int K) {
  gemm_body(A, lda, B, ldb, bias, Cmat, ldc, M, K,
            blockIdx.x * BM, blockIdx.y * BN);
}

// Fused Q/K/V head projection: blockIdx.z selects which of the three.
// Output is compact N x CH (ldc = CH), Nc = CH so grid.y = CH/BN = 2.
__global__ __launch_bounds__(256) void gemm_qkv(
    const float* __restrict__ A, int lda,
    const float* __restrict__ WQ, const float* __restrict__ WK,
    const float* __restrict__ WV, int ldb,
    const float* __restrict__ bQ, const float* __restrict__ bK,
    const float* __restrict__ bV,
    float* __restrict__ OQ, float* __restrict__ OK_, float* __restrict__ OV,
    int M, int K) {
  const float* B    = (blockIdx.z == 0) ? WQ : (blockIdx.z == 1) ? WK : WV;
  const float* bias = (blockIdx.z == 0) ? bQ : (blockIdx.z == 1) ? bK : bV;
  float*       C    = (blockIdx.z == 0) ? OQ : (blockIdx.z == 1) ? OK_ : OV;
  gemm_body(A, lda, B, ldb, bias, C, CH, M, K,
            blockIdx.x * BM, blockIdx.y * BN);
}

// ---------------------------------------------------------------------------
// Small utility kernels
// ---------------------------------------------------------------------------
__global__ void zero_ints(int* __restrict__ p, int n) {
  int i = blockIdx.x * blockDim.x + threadIdx.x;
  if (i < n) p[i] = 0;
}

__global__ void elu_kernel(float* __restrict__ d, int n) {
  int i = blockIdx.x * blockDim.x + threadIdx.x;
  if (i < n) {
    float v = d[i];
    d[i] = v > 0.f ? v : expm1f(v);
  }
}

// ---------------------------------------------------------------------------
// CSR-by-dst build
// ---------------------------------------------------------------------------
__global__ void hist_kernel(const int* __restrict__ dst, int* __restrict__ deg) {
  int e = blockIdx.x * blockDim.x + threadIdx.x;
  if (e < EDGES) atomicAdd(&deg[dst[e]], 1);
}

__global__ __launch_bounds__(1024) void scan_kernel(
    const int* __restrict__ deg, int* __restrict__ indptr) {
  __shared__ int buf[1024];
  __shared__ int carry;
  int t = threadIdx.x;
  if (t == 0) { carry = 0; indptr[0] = 0; }
  __syncthreads();
  for (int base = 0; base < N_NODES; base += 1024) {
    int i = base + t;
    int v = (i < N_NODES) ? deg[i] : 0;
    buf[t] = v;
    __syncthreads();
    for (int off = 1; off < 1024; off <<= 1) {
      int a = buf[t];
      int b = (t >= off) ? buf[t - off] : 0;
      __syncthreads();
      buf[t] = a + b;
      __syncthreads();
    }
    if (i < N_NODES) indptr[i + 1] = carry + buf[t];  // inclusive -> indptr[i+1]
    int total = buf[1023];
    __syncthreads();
    if (t == 0) carry += total;
    __syncthreads();
  }
}

__global__ void cursor_init(const int* __restrict__ indptr, int* __restrict__ cursor) {
  int i = blockIdx.x * blockDim.x + threadIdx.x;
  if (i < N_NODES) cursor[i] = indptr[i];
}

__global__ void scatter_kernel(const int* __restrict__ src, const int* __restrict__ dst,
                               int* __restrict__ cursor, int* __restrict__ csr) {
  int e = blockIdx.x * blockDim.x + threadIdx.x;
  if (e < EDGES) {
    int pos = atomicAdd(&cursor[dst[e]], 1);
    csr[pos] = src[e];
  }
}

__global__ void bounds_kernel(const int* __restrict__ batch,
                              int* __restrict__ gstart, int* __restrict__ gend) {
  int i = blockIdx.x * blockDim.x + threadIdx.x;
  if (i >= N_NODES) return;
  int b = batch[i];
  if (i == 0 || batch[i - 1] != b) gstart[b] = i;
  if (i == N_NODES - 1 || batch[i + 1] != b) gend[b] = i + 1;
}

// ---------------------------------------------------------------------------
// Per-head attention: one wave per node, online softmax over in-edges (CSR).
// dest[i*destStride + destOff + c] += scale * msg[c]   (dest pre-filled with
// the skip projection, ELU applied in a later pass).
// ---------------------------------------------------------------------------
__global__ __launch_bounds__(256) void attn_head(
    const float* __restrict__ Qh, const float* __restrict__ Kh,
    const float* __restrict__ Vh, const int* __restrict__ indptr,
    const int* __restrict__ csr, float* __restrict__ dest,
    int destStride, int destOff, float scale) {
  int wid = threadIdx.x >> 6;
  int lane = threadIdx.x & 63;
  int i = blockIdx.x * 4 + wid;
  if (i >= N_NODES) return;
  const int qb = i * CH;
  float q0 = Qh[qb + lane], q1 = Qh[qb + lane + 64];
  int beg = indptr[i], end = indptr[i + 1];
  float m = -INFINITY, ssum = 0.f, a0 = 0.f, a1 = 0.f;
  for (int e = beg; e < end; ++e) {
    int j = csr[e];
    int kb = j * CH;
    float k0 = Kh[kb + lane], k1 = Kh[kb + lane + 64];
    float p = q0 * k0 + q1 * k1;
#pragma unroll
    for (int off = 32; off > 0; off >>= 1) p += __shfl_xor(p, off);
    float alpha = p * 0.08838834764831845f;  // 1/sqrt(128)
    float mn = fmaxf(m, alpha);
    float sc = expf(m - mn);    // first iter: exp(-inf)=0
    float w = expf(alpha - mn);
    float v0 = Vh[kb + lane], v1 = Vh[kb + lane + 64];
    ssum = ssum * sc + w;
    a0 = a0 * sc + w * v0;
    a1 = a1 * sc + w * v1;
    m = mn;
  }
  float inv = scale / (ssum + 1e-16f);  // empty segment: msg = 0
  size_t db = (size_t)i * destStride + destOff;
  dest[db + lane]      += inv * a0;
  dest[db + lane + 64] += inv * a1;
}

// ---------------------------------------------------------------------------
// Per-graph mean pool + 128x10 classifier + log_softmax. One block per graph.
// ---------------------------------------------------------------------------
__global__ __launch_bounds__(128) void pool_cls(
    const float* __restrict__ H2, const int* __restrict__ gstart,
    const int* __restrict__ gend, const float* __restrict__ Wfc,
    const float* __restrict__ bfc, float* __restrict__ out) {
  int g = blockIdx.x;
  int t = threadIdx.x;
  int s0 = gstart[g], e0 = gend[g];
  float sum = 0.f;
  for (int i = s0; i < e0; ++i) sum += H2[(size_t)i * CH + t];
  float cnt = fmaxf((float)(e0 - s0), 1.f);
  __shared__ float p[CH];
  __shared__ float red[CH];
  __shared__ float logits[NCLS];
  p[t] = sum / cnt;
  for (int c = 0; c < NCLS; ++c) {
    __syncthreads();
    red[t] = p[t] * Wfc[t * NCLS + c];
    __syncthreads();
    for (int off = 64; off > 0; off >>= 1) {
      if (t < off) red[t] += red[t + off];
      __syncthreads();
    }
    if (t == 0) logits[c] = red[0] + bfc[c];
  }
  __syncthreads();
  if (t == 0) {
    float mx = -INFINITY;
    for (int c = 0; c < NCLS; ++c) mx = fmaxf(mx, logits[c]);
    float se = 0.f;
    for (int c = 0; c < NCLS; ++c) se += expf(logits[c] - mx);
    float ls = mx + logf(se);
    for (int c = 0; c < NCLS; ++c) out[g * NCLS + c] = logits[c] - ls;
  }
}

// ---------------------------------------------------------------------------
extern "C" void kernel_launch(void* const* d_in, const int* in_sizes, int n_in,
                              void* d_out, int out_size, void* d_ws, size_t ws_size,
                              hipStream_t stream) {
  const float* x    = (const float*)d_in[0];
  const int*   ei   = (const int*)d_in[1];
  const int*   batch= (const int*)d_in[2];
  const float* Wq1 = (const float*)d_in[3];  const float* bq1 = (const float*)d_in[4];
  const float* Wk1 = (const float*)d_in[5];  const float* bk1 = (const float*)d_in[6];
  const float* Wv1 = (const float*)d_in[7];  const float* bv1 = (const float*)d_in[8];
  const float* Ws1 = (const float*)d_in[9];  const float* bs1 = (const float*)d_in[10];
  const float* Wq2 = (const float*)d_in[11]; const float* bq2 = (const float*)d_in[12];
  const float* Wk2 = (const float*)d_in[13]; const float* bk2 = (const float*)d_in[14];
  const float* Wv2 = (const float*)d_in[15]; const float* bv2 = (const float*)d_in[16];
  const float* Ws2 = (const float*)d_in[17]; const float* bs2 = (const float*)d_in[18];
  const float* Wfc = (const float*)d_in[19]; const float* bfc = (const float*)d_in[20];
  float* out = (float*)d_out;

  // Workspace layout (~206 MB total; ws re-poisoned each call, we init all we use)
  float* H1 = (float*)d_ws;                      // N x 512
  float* H2 = H1 + (size_t)N_NODES * HID;        // N x 128
  float* Qh = H2 + (size_t)N_NODES * CH;         // N x 128 (per-head transient)
  float* Kh = Qh + (size_t)N_NODES * CH;
  float* Vh = Kh + (size_t)N_NODES * CH;
  int* deg    = (int*)(Vh + (size_t)N_NODES * CH);
  int* indptr = deg + N_NODES;
  int* cursor = indptr + N_NODES + 1;
  int* csr    = cursor + N_NODES;
  int* gstart = csr + EDGES;
  int* gend   = gstart + NGRAPH;

  const int* srcp = ei;
  const int* dstp = ei + EDGES;

  // ---- CSR build (same graph for both layers) ----
  zero_ints<<<(N_NODES + 255) / 256, 256, 0, stream>>>(deg, N_NODES);
  zero_ints<<<2, 256, 0, stream>>>(gstart, 2 * NGRAPH);
  hist_kernel<<<(EDGES + 255) / 256, 256, 0, stream>>>(dstp, deg);
  scan_kernel<<<1, 1024, 0, stream>>>(deg, indptr);
  cursor_init<<<(N_NODES + 255) / 256, 256, 0, stream>>>(indptr, cursor);
  scatter_kernel<<<(EDGES + 255) / 256, 256, 0, stream>>>(srcp, dstp, cursor, csr);
  bounds_kernel<<<(N_NODES + 255) / 256, 256, 0, stream>>>(batch, gstart, gend);

  const int gx = (N_NODES + BM - 1) / BM;   // 782
  dim3 blk(256);

  // ---- layer 1: skip into H1, then per-head QKV + attention accumulate ----
  gemm_bias<<<dim3(gx, HID / BN), blk, 0, stream>>>(x, FEAT, Ws1, HID, bs1,
                                                    H1, HID, N_NODES, FEAT);
  for (int h = 0; h < HEADS; ++h) {
    gemm_qkv<<<dim3(gx, CH / BN, 3), blk, 0, stream>>>(
        x, FEAT, Wq1 + h * CH, Wk1 + h * CH, Wv1 + h * CH, HID,
        bq1 + h * CH, bk1 + h * CH, bv1 + h * CH, Qh, Kh, Vh, N_NODES, FEAT);
    attn_head<<<(N_NODES + 3) / 4, 256, 0, stream>>>(
        Qh, Kh, Vh, indptr, csr, H1, HID, h * CH, 1.0f);
  }
  elu_kernel<<<(N_NODES * HID + 255) / 256, 256, 0, stream>>>(H1, N_NODES * HID);

  // ---- layer 2: skip into H2, per-head QKV from H1, mean over heads ----
  gemm_bias<<<dim3(gx, CH / BN), blk, 0, stream>>>(H1, HID, Ws2, CH, bs2,
                                                   H2, CH, N_NODES, HID);
  for (int h = 0; h < HEADS; ++h) {
    gemm_qkv<<<dim3(gx, CH / BN, 3), blk, 0, stream>>>(
        H1, HID, Wq2 + h * CH, Wk2 + h * CH, Wv2 + h * CH, HID,
        bq2 + h * CH, bk2 + h * CH, bv2 + h * CH, Qh, Kh, Vh, N_NODES, HID);
    attn_head<<<(N_NODES + 3) / 4, 256, 0, stream>>>(
        Qh, Kh, Vh, indptr, csr, H2, CH, 0, 0.25f);
  }
  elu_kernel<<<(N_NODES * CH + 255) / 256, 256, 0, stream>>>(H2, N_NODES * CH);

  // ---- pool + classify ----
  pool_cls<<<NGRAPH, CH, 0, stream>>>(H2, gstart, gend, Wfc, bfc, out);
}

// Round 3
// 1045.556 us; speedup vs baseline: 3.0857x; 3.0857x over previous
//
#include <hip/hip_runtime.h>
#include <math.h>
#include <stdint.h>

#define N_NODES 50000
#define FEAT    256
#define EDGES   200000
#define HEADS   4
#define CH      128
#define HID     512   // HEADS*CH
#define NGRAPH  256
#define NCLS    10

typedef unsigned short ushort_t;
typedef unsigned int uint_t;
typedef __attribute__((ext_vector_type(8))) short bf16x8;
typedef __attribute__((ext_vector_type(4))) float f32x4;

__device__ __forceinline__ ushort_t f2bf(float f) {  // round-to-nearest-even
  uint_t u = __float_as_uint(f);
  u += 0x7FFF + ((u >> 16) & 1);
  return (ushort_t)(u >> 16);
}
__device__ __forceinline__ float bf2f(ushort_t h) {
  return __uint_as_float(((uint_t)h) << 16);
}

// ---------------------------------------------------------------------------
// bf16 MFMA GEMM (m97 structure): C[M,N] = A[M,K] @ Bt[N,K]^T + bias
// 128x128 tile, BK=32, 256 threads (4 waves, 2x2), 4x4 16x16x32 tiles/wave.
// LDS tiles are XOR-chunk-swizzled ([row][chunk^( row&3)]) so both
// global_load_lds staging (lane*16B contiguous) and ds_read_b128 fragment
// reads stay <=2-way bank-conflicted.
// ---------------------------------------------------------------------------
__device__ __forceinline__ void storeC(float* C, size_t idx, float v) { C[idx] = v; }
__device__ __forceinline__ void storeC(ushort_t* C, size_t idx, float v) { C[idx] = f2bf(v); }

template <typename CT>
__global__ __launch_bounds__(256) void gemm_bt(
    const ushort_t* __restrict__ A, const ushort_t* __restrict__ Bt,
    const float* __restrict__ bias, CT* __restrict__ C, int ldc,
    int M, int K) {
  __shared__ __align__(16) ushort_t sA[128 * 32];
  __shared__ __align__(16) ushort_t sB[128 * 32];
  const int tid = threadIdx.x;
  const int lane = tid & 63, wave = tid >> 6;
  const int wr = wave >> 1, wc = wave & 1;
  const int rowBase = blockIdx.x * 128, colBase = blockIdx.y * 128;
  f32x4 acc[4][4] = {};

  for (int k0 = 0; k0 < K; k0 += 32) {
#pragma unroll
    for (int j = 0; j < 2; ++j) {
      int rl = j * 64 + (tid >> 2);       // local row/col 0..127
      int slot = tid & 3;                 // which 16B chunk slot this lane fills
      int cg = slot ^ (rl & 3);           // swizzle: global chunk landing here
      {
        int row = rowBase + rl;
        row = row < M ? row : M - 1;      // clamp tail (epilogue guards writes)
        const ushort_t* gp = A + (size_t)row * K + k0 + cg * 8;
        __builtin_amdgcn_global_load_lds(
            (const __attribute__((address_space(1))) uint_t*)gp,
            (__attribute__((address_space(3))) uint_t*)(sA + j * 2048 + tid * 8),
            16, 0, 0);
      }
      {
        int n = colBase + rl;             // N is always a multiple of 128
        const ushort_t* gp = Bt + (size_t)n * K + k0 + cg * 8;
        __builtin_amdgcn_global_load_lds(
            (const __attribute__((address_space(1))) uint_t*)gp,
            (__attribute__((address_space(3))) uint_t*)(sB + j * 2048 + tid * 8),
            16, 0, 0);
      }
    }
    __syncthreads();
    const int fr = lane & 15, c0 = lane >> 4;   // frag row, 16B k-chunk
    bf16x8 af[4], bfr[4];
#pragma unroll
    for (int i = 0; i < 4; ++i) {
      int r = wr * 64 + i * 16 + fr;
      af[i] = *(const bf16x8*)(sA + r * 32 + ((c0 ^ (r & 3)) * 8));
      int n = wc * 64 + i * 16 + fr;
      bfr[i] = *(const bf16x8*)(sB + n * 32 + ((c0 ^ (n & 3)) * 8));
    }
#pragma unroll
    for (int i = 0; i < 4; ++i)
#pragma unroll
      for (int j = 0; j < 4; ++j)
        acc[i][j] = __builtin_amdgcn_mfma_f32_16x16x32_bf16(af[i], bfr[j], acc[i][j], 0, 0, 0);
    __syncthreads();
  }

  // epilogue: C/D layout col=lane&15, row=(lane>>4)*4+reg (m89-verified)
  const int fc = lane & 15, rq = lane >> 4;
#pragma unroll
  for (int i = 0; i < 4; ++i) {
#pragma unroll
    for (int j = 0; j < 4; ++j) {
      int col = colBase + wc * 64 + j * 16 + fc;
      float bv = bias[col];
#pragma unroll
      for (int r = 0; r < 4; ++r) {
        int row = rowBase + wr * 64 + i * 16 + rq * 4 + r;
        if (row < M) storeC(C, (size_t)row * ldc + col, acc[i][j][r] + bv);
      }
    }
  }
}

// ---------------------------------------------------------------------------
// Prep kernels: transpose weights to [N,K] bf16, build per-head bias arrays.
// ---------------------------------------------------------------------------
__global__ void cvt_bf16_kernel(const float* __restrict__ in, ushort_t* __restrict__ out, int n4) {
  int i = blockIdx.x * blockDim.x + threadIdx.x;
  if (i >= n4) return;
  float4 f = *(const float4*)(in + (size_t)i * 4);
  uint_t lo = (uint_t)f2bf(f.x) | ((uint_t)f2bf(f.y) << 16);
  uint_t hi = (uint_t)f2bf(f.z) | ((uint_t)f2bf(f.w) << 16);
  ((uint2*)out)[i] = make_uint2(lo, hi);
}

// layer1: Wt[4][512][256] rows = [q|k|v|s] per head; Bh[4][512]
__global__ void prep_l1(const float* __restrict__ Wq, const float* __restrict__ Wk,
                        const float* __restrict__ Wv, const float* __restrict__ Ws,
                        const float* __restrict__ bq, const float* __restrict__ bk,
                        const float* __restrict__ bv, const float* __restrict__ bs,
                        ushort_t* __restrict__ Wt, float* __restrict__ Bh) {
  int idx = blockIdx.x * blockDim.x + threadIdx.x;
  if (idx >= HEADS * HID * FEAT) return;
  int k = idx & (FEAT - 1);
  int t = idx >> 8;
  int n = t & (HID - 1);
  int h = t >> 9;
  int sel = n >> 7;
  int c = h * CH + (n & (CH - 1));
  const float* W = sel == 0 ? Wq : sel == 1 ? Wk : sel == 2 ? Wv : Ws;
  Wt[idx] = f2bf(W[(size_t)k * HID + c]);
  if (k == 0) {
    const float* b = sel == 0 ? bq : sel == 1 ? bk : sel == 2 ? bv : bs;
    Bh[h * HID + n] = b[c];
  }
}

// layer2 qkv: Wt[4][384][512] rows = [q|k|v] per head; Bh[4][384]
__global__ void prep_l2(const float* __restrict__ Wq, const float* __restrict__ Wk,
                        const float* __restrict__ Wv,
                        const float* __restrict__ bq, const float* __restrict__ bk,
                        const float* __restrict__ bv,
                        ushort_t* __restrict__ Wt, float* __restrict__ Bh) {
  int idx = blockIdx.x * blockDim.x + threadIdx.x;
  if (idx >= HEADS * 384 * HID) return;
  int k = idx & (HID - 1);
  int t = idx >> 9;
  int n = t % 384;
  int h = t / 384;
  int sel = n >> 7;
  int c = h * CH + (n & (CH - 1));
  const float* W = sel == 0 ? Wq : sel == 1 ? Wk : Wv;
  Wt[idx] = f2bf(W[(size_t)k * HID + c]);
  if (k == 0) {
    const float* b = sel == 0 ? bq : sel == 1 ? bk : bv;
    Bh[h * 384 + n] = b[c];
  }
}

// layer2 skip: Ws2 [512,128] -> Ws2t [128][512]
__global__ void prep_skip2(const float* __restrict__ Ws, ushort_t* __restrict__ Wt) {
  int idx = blockIdx.x * blockDim.x + threadIdx.x;
  if (idx >= CH * HID) return;
  int k = idx & (HID - 1);
  int n = idx >> 9;
  Wt[idx] = f2bf(Ws[(size_t)k * CH + n]);
}

// ---------------------------------------------------------------------------
// Small utility kernels
// ---------------------------------------------------------------------------
__global__ void zero_ints(int* __restrict__ p, int n) {
  int i = blockIdx.x * blockDim.x + threadIdx.x;
  if (i < n) p[i] = 0;
}

__global__ void elu_kernel(float* __restrict__ d, int n) {
  int i = blockIdx.x * blockDim.x + threadIdx.x;
  if (i < n) {
    float v = d[i];
    d[i] = v > 0.f ? v : expm1f(v);
  }
}

// ---------------------------------------------------------------------------
// CSR-by-dst build
// ---------------------------------------------------------------------------
__global__ void hist_kernel(const int* __restrict__ dst, int* __restrict__ deg) {
  int e = blockIdx.x * blockDim.x + threadIdx.x;
  if (e < EDGES) atomicAdd(&deg[dst[e]], 1);
}

__global__ __launch_bounds__(1024) void scan_kernel(
    const int* __restrict__ deg, int* __restrict__ indptr) {
  __shared__ int buf[1024];
  __shared__ int carry;
  int t = threadIdx.x;
  if (t == 0) { carry = 0; indptr[0] = 0; }
  __syncthreads();
  for (int base = 0; base < N_NODES; base += 1024) {
    int i = base + t;
    int v = (i < N_NODES) ? deg[i] : 0;
    buf[t] = v;
    __syncthreads();
    for (int off = 1; off < 1024; off <<= 1) {
      int a = buf[t];
      int b = (t >= off) ? buf[t - off] : 0;
      __syncthreads();
      buf[t] = a + b;
      __syncthreads();
    }
    if (i < N_NODES) indptr[i + 1] = carry + buf[t];
    int total = buf[1023];
    __syncthreads();
    if (t == 0) carry += total;
    __syncthreads();
  }
}

__global__ void cursor_init(const int* __restrict__ indptr, int* __restrict__ cursor) {
  int i = blockIdx.x * blockDim.x + threadIdx.x;
  if (i < N_NODES) cursor[i] = indptr[i];
}

__global__ void scatter_kernel(const int* __restrict__ src, const int* __restrict__ dst,
                               int* __restrict__ cursor, int* __restrict__ csr) {
  int e = blockIdx.x * blockDim.x + threadIdx.x;
  if (e < EDGES) {
    int pos = atomicAdd(&cursor[dst[e]], 1);
    csr[pos] = src[e];
  }
}

__global__ void bounds_kernel(const int* __restrict__ batch,
                              int* __restrict__ gstart, int* __restrict__ gend) {
  int i = blockIdx.x * blockDim.x + threadIdx.x;
  if (i >= N_NODES) return;
  int b = batch[i];
  if (i == 0 || batch[i - 1] != b) gstart[b] = i;
  if (i == N_NODES - 1 || batch[i + 1] != b) gend[b] = i + 1;
}

// ---------------------------------------------------------------------------
// Attention: one wave per node, online softmax over in-edges (CSR).
// Q/K/V bf16, channels 2*lane / 2*lane+1 per lane (one dword per operand).
// ---------------------------------------------------------------------------
__device__ __forceinline__ void attn_loop(
    const ushort_t* __restrict__ QKV, int stride, int kOff, int vOff,
    int i, int lane, const int* __restrict__ indptr, const int* __restrict__ csr,
    float& a0, float& a1, float& ssum) {
  const ushort_t* qp = QKV + (size_t)i * stride;
  uint_t qw = *(const uint_t*)(qp + 2 * lane);
  float q0 = bf2f((ushort_t)qw), q1 = bf2f((ushort_t)(qw >> 16));
  int beg = indptr[i], end = indptr[i + 1];
  float m = -INFINITY;
  ssum = 0.f; a0 = 0.f; a1 = 0.f;
  for (int e = beg; e < end; ++e) {
    int j = csr[e];
    const ushort_t* jp = QKV + (size_t)j * stride;
    uint_t kw = *(const uint_t*)(jp + kOff + 2 * lane);
    uint_t vw = *(const uint_t*)(jp + vOff + 2 * lane);
    float p = q0 * bf2f((ushort_t)kw) + q1 * bf2f((ushort_t)(kw >> 16));
#pragma unroll
    for (int off = 32; off > 0; off >>= 1) p += __shfl_xor(p, off);
    float alpha = p * 0.08838834764831845f;  // 1/sqrt(128)
    float mn = fmaxf(m, alpha);
    float sc = expf(m - mn);    // first iter: exp(-inf)=0
    float w = expf(alpha - mn);
    ssum = ssum * sc + w;
    a0 = a0 * sc + w * bf2f((ushort_t)vw);
    a1 = a1 * sc + w * bf2f((ushort_t)(vw >> 16));
    m = mn;
  }
}

// layer 1: per-head col slice of H1b is exclusive -> fuse skip-add + ELU here
__global__ __launch_bounds__(256) void attn1_kernel(
    const ushort_t* __restrict__ QKVS, const int* __restrict__ indptr,
    const int* __restrict__ csr, ushort_t* __restrict__ H1b, int hOff) {
  int wid = threadIdx.x >> 6, lane = threadIdx.x & 63;
  int i = blockIdx.x * 4 + wid;
  if (i >= N_NODES) return;
  float a0, a1, ssum;
  attn_loop(QKVS, HID, CH, 2 * CH, i, lane, indptr, csr, a0, a1, ssum);
  float inv = 1.f / (ssum + 1e-16f);
  uint_t sw = *(const uint_t*)(QKVS + (size_t)i * HID + 3 * CH + 2 * lane);
  float o0 = a0 * inv + bf2f((ushort_t)sw);
  float o1 = a1 * inv + bf2f((ushort_t)(sw >> 16));
  o0 = o0 > 0.f ? o0 : expm1f(o0);
  o1 = o1 > 0.f ? o1 : expm1f(o1);
  uint_t ow = (uint_t)f2bf(o0) | ((uint_t)f2bf(o1) << 16);
  *(uint_t*)(H1b + (size_t)i * HID + hOff + 2 * lane) = ow;
}

// layer 2: heads share cols -> accumulate mean into fp32 S2 (skip pre-filled)
__global__ __launch_bounds__(256) void attn2_kernel(
    const ushort_t* __restrict__ QKV, const int* __restrict__ indptr,
    const int* __restrict__ csr, float* __restrict__ S2) {
  int wid = threadIdx.x >> 6, lane = threadIdx.x & 63;
  int i = blockIdx.x * 4 + wid;
  if (i >= N_NODES) return;
  float a0, a1, ssum;
  attn_loop(QKV, 3 * CH, CH, 2 * CH, i, lane, indptr, csr, a0, a1, ssum);
  float inv = 0.25f / (ssum + 1e-16f);
  float2* p = (float2*)(S2 + (size_t)i * CH) + lane;
  float2 v = *p;
  v.x += a0 * inv;
  v.y += a1 * inv;
  *p = v;
}

// ---------------------------------------------------------------------------
// Per-graph mean pool + 128x10 classifier + log_softmax. One block per graph.
// ---------------------------------------------------------------------------
__global__ __launch_bounds__(128) void pool_cls(
    const float* __restrict__ H2, const int* __restrict__ gstart,
    const int* __restrict__ gend, const float* __restrict__ Wfc,
    const float* __restrict__ bfc, float* __restrict__ out) {
  int g = blockIdx.x;
  int t = threadIdx.x;
  int s0 = gstart[g], e0 = gend[g];
  float sum = 0.f;
  for (int i = s0; i < e0; ++i) sum += H2[(size_t)i * CH + t];
  float cnt = fmaxf((float)(e0 - s0), 1.f);
  __shared__ float p[CH];
  __shared__ float red[CH];
  __shared__ float logits[NCLS];
  p[t] = sum / cnt;
  for (int c = 0; c < NCLS; ++c) {
    __syncthreads();
    red[t] = p[t] * Wfc[t * NCLS + c];
    __syncthreads();
    for (int off = 64; off > 0; off >>= 1) {
      if (t < off) red[t] += red[t + off];
      __syncthreads();
    }
    if (t == 0) logits[c] = red[0] + bfc[c];
  }
  __syncthreads();
  if (t == 0) {
    float mx = -INFINITY;
    for (int c = 0; c < NCLS; ++c) mx = fmaxf(mx, logits[c]);
    float se = 0.f;
    for (int c = 0; c < NCLS; ++c) se += expf(logits[c] - mx);
    float ls = mx + logf(se);
    for (int c = 0; c < NCLS; ++c) out[g * NCLS + c] = logits[c] - ls;
  }
}

// ---------------------------------------------------------------------------
extern "C" void kernel_launch(void* const* d_in, const int* in_sizes, int n_in,
                              void* d_out, int out_size, void* d_ws, size_t ws_size,
                              hipStream_t stream) {
  const float* x    = (const float*)d_in[0];
  const int*   ei   = (const int*)d_in[1];
  const int*   batch= (const int*)d_in[2];
  const float* Wq1 = (const float*)d_in[3];  const float* bq1 = (const float*)d_in[4];
  const float* Wk1 = (const float*)d_in[5];  const float* bk1 = (const float*)d_in[6];
  const float* Wv1 = (const float*)d_in[7];  const float* bv1 = (const float*)d_in[8];
  const float* Ws1 = (const float*)d_in[9];  const float* bs1 = (const float*)d_in[10];
  const float* Wq2 = (const float*)d_in[11]; const float* bq2 = (const float*)d_in[12];
  const float* Wk2 = (const float*)d_in[13]; const float* bk2 = (const float*)d_in[14];
  const float* Wv2 = (const float*)d_in[15]; const float* bv2 = (const float*)d_in[16];
  const float* Ws2 = (const float*)d_in[17]; const float* bs2 = (const float*)d_in[18];
  const float* Wfc = (const float*)d_in[19]; const float* bfc = (const float*)d_in[20];
  float* out = (float*)d_out;

  // Workspace (~158 MB)
  ushort_t* xb    = (ushort_t*)d_ws;                    // N x 256 bf16
  ushort_t* QKVSh = xb + (size_t)N_NODES * FEAT;        // N x 512 bf16 (per-head q|k|v|s, reused)
  ushort_t* H1b   = QKVSh + (size_t)N_NODES * HID;      // N x 512 bf16
  float*    S2    = (float*)(H1b + (size_t)N_NODES * HID); // N x 128 fp32 (becomes H2)
  ushort_t* W1t   = (ushort_t*)(S2 + (size_t)N_NODES * CH); // 4*512*256
  float*    Bh1   = (float*)(W1t + HEADS * HID * FEAT);     // 4*512
  ushort_t* W2t   = (ushort_t*)(Bh1 + HEADS * HID);         // 4*384*512
  float*    Bh2   = (float*)(W2t + HEADS * 384 * HID);      // 4*384
  ushort_t* Ws2t  = (ushort_t*)(Bh2 + HEADS * 384);         // 128*512
  int* deg    = (int*)(Ws2t + CH * HID);
  int* indptr = deg + N_NODES;
  int* cursor = indptr + N_NODES + 1;
  int* csr    = cursor + N_NODES;
  int* gstart = csr + EDGES;
  int* gend   = gstart + NGRAPH;

  const int* srcp = ei;
  const int* dstp = ei + EDGES;

  // ---- prep: bf16 conversions / weight transposes ----
  cvt_bf16_kernel<<<(N_NODES * FEAT / 4 + 255) / 256, 256, 0, stream>>>(x, xb, N_NODES * FEAT / 4);
  prep_l1<<<(HEADS * HID * FEAT + 255) / 256, 256, 0, stream>>>(
      Wq1, Wk1, Wv1, Ws1, bq1, bk1, bv1, bs1, W1t, Bh1);
  prep_l2<<<(HEADS * 384 * HID + 255) / 256, 256, 0, stream>>>(
      Wq2, Wk2, Wv2, bq2, bk2, bv2, W2t, Bh2);
  prep_skip2<<<(CH * HID + 255) / 256, 256, 0, stream>>>(Ws2, Ws2t);

  // ---- CSR build ----
  zero_ints<<<(N_NODES + 255) / 256, 256, 0, stream>>>(deg, N_NODES);
  zero_ints<<<2, 256, 0, stream>>>(gstart, 2 * NGRAPH);
  hist_kernel<<<(EDGES + 255) / 256, 256, 0, stream>>>(dstp, deg);
  scan_kernel<<<1, 1024, 0, stream>>>(deg, indptr);
  cursor_init<<<(N_NODES + 255) / 256, 256, 0, stream>>>(indptr, cursor);
  scatter_kernel<<<(EDGES + 255) / 256, 256, 0, stream>>>(srcp, dstp, cursor, csr);
  bounds_kernel<<<(N_NODES + 255) / 256, 256, 0, stream>>>(batch, gstart, gend);

  const int gx = (N_NODES + 127) / 128;  // 391

  // ---- layer 1: per head, GEMM (q|k|v|s) then attention (fused skip+ELU) ----
  for (int h = 0; h < HEADS; ++h) {
    gemm_bt<ushort_t><<<dim3(gx, 4), 256, 0, stream>>>(
        xb, W1t + (size_t)h * HID * FEAT, Bh1 + h * HID, QKVSh, HID, N_NODES, FEAT);
    attn1_kernel<<<(N_NODES + 3) / 4, 256, 0, stream>>>(QKVSh, indptr, csr, H1b, h * CH);
  }

  // ---- layer 2: skip first (fp32 S2), then per-head GEMM + attention ----
  gemm_bt<float><<<dim3(gx, 1), 256, 0, stream>>>(
      H1b, Ws2t, bs2, S2, CH, N_NODES, HID);
  for (int h = 0; h < HEADS; ++h) {
    gemm_bt<ushort_t><<<dim3(gx, 3), 256, 0, stream>>>(
        H1b, W2t + (size_t)h * 384 * HID, Bh2 + h * 384, QKVSh, 384, N_NODES, HID);
    attn2_kernel<<<(N_NODES + 3) / 4, 256, 0, stream>>>(QKVSh, indptr, csr, S2);
  }
  elu_kernel<<<(N_NODES * CH + 255) / 256, 256, 0, stream>>>(S2, N_NODES * CH);

  // ---- pool + classify ----
  pool_cls<<<NGRAPH, CH, 0, stream>>>(S2, gstart, gend, Wfc, bfc, out);
}

// Round 4
// 864.598 us; speedup vs baseline: 3.7315x; 1.2093x over previous
//
#include <hip/hip_runtime.h>
#include <math.h>
#include <stdint.h>

#define N_NODES 50000
#define FEAT    256
#define EDGES   200000
#define HEADS   4
#define CH      128
#define HID     512   // HEADS*CH
#define NGRAPH  256
#define NCLS    10

typedef unsigned short ushort_t;
typedef unsigned int uint_t;
typedef __attribute__((ext_vector_type(8))) short bf16x8;
typedef __attribute__((ext_vector_type(4))) float f32x4;

__device__ __forceinline__ ushort_t f2bf(float f) {  // round-to-nearest-even
  uint_t u = __float_as_uint(f);
  u += 0x7FFF + ((u >> 16) & 1);
  return (ushort_t)(u >> 16);
}
__device__ __forceinline__ float bf2f(ushort_t h) {
  return __uint_as_float(((uint_t)h) << 16);
}

// ---------------------------------------------------------------------------
// bf16 MFMA GEMM (m97 structure): C[M,N] = A[M,K] @ Bt[N,K]^T + bias
// 128x128 tile, BK=32, 256 threads (4 waves, 2x2), 4x4 16x16x32 tiles/wave.
// XOR-chunk-swizzled LDS; global_load_lds width=16 staging.
// ---------------------------------------------------------------------------
__device__ __forceinline__ void storeC(float* C, size_t idx, float v) { C[idx] = v; }
__device__ __forceinline__ void storeC(ushort_t* C, size_t idx, float v) { C[idx] = f2bf(v); }

template <typename CT>
__global__ __launch_bounds__(256) void gemm_bt(
    const ushort_t* __restrict__ A, const ushort_t* __restrict__ Bt,
    const float* __restrict__ bias, CT* __restrict__ C, int ldc,
    int M, int K) {
  __shared__ __align__(16) ushort_t sA[128 * 32];
  __shared__ __align__(16) ushort_t sB[128 * 32];
  const int tid = threadIdx.x;
  const int lane = tid & 63, wave = tid >> 6;
  const int wr = wave >> 1, wc = wave & 1;
  const int rowBase = blockIdx.x * 128, colBase = blockIdx.y * 128;
  f32x4 acc[4][4] = {};

  for (int k0 = 0; k0 < K; k0 += 32) {
#pragma unroll
    for (int j = 0; j < 2; ++j) {
      int rl = j * 64 + (tid >> 2);       // local row/col 0..127
      int slot = tid & 3;
      int cg = slot ^ (rl & 3);           // swizzle chunk
      {
        int row = rowBase + rl;
        row = row < M ? row : M - 1;      // clamp tail (epilogue guards writes)
        const ushort_t* gp = A + (size_t)row * K + k0 + cg * 8;
        __builtin_amdgcn_global_load_lds(
            (const __attribute__((address_space(1))) uint_t*)gp,
            (__attribute__((address_space(3))) uint_t*)(sA + j * 2048 + tid * 8),
            16, 0, 0);
      }
      {
        int n = colBase + rl;             // N multiple of 128 always
        const ushort_t* gp = Bt + (size_t)n * K + k0 + cg * 8;
        __builtin_amdgcn_global_load_lds(
            (const __attribute__((address_space(1))) uint_t*)gp,
            (__attribute__((address_space(3))) uint_t*)(sB + j * 2048 + tid * 8),
            16, 0, 0);
      }
    }
    __syncthreads();
    const int fr = lane & 15, c0 = lane >> 4;
    bf16x8 af[4], bfr[4];
#pragma unroll
    for (int i = 0; i < 4; ++i) {
      int r = wr * 64 + i * 16 + fr;
      af[i] = *(const bf16x8*)(sA + r * 32 + ((c0 ^ (r & 3)) * 8));
      int n = wc * 64 + i * 16 + fr;
      bfr[i] = *(const bf16x8*)(sB + n * 32 + ((c0 ^ (n & 3)) * 8));
    }
#pragma unroll
    for (int i = 0; i < 4; ++i)
#pragma unroll
      for (int j = 0; j < 4; ++j)
        acc[i][j] = __builtin_amdgcn_mfma_f32_16x16x32_bf16(af[i], bfr[j], acc[i][j], 0, 0, 0);
    __syncthreads();
  }

  const int fc = lane & 15, rq = lane >> 4;
#pragma unroll
  for (int i = 0; i < 4; ++i) {
#pragma unroll
    for (int j = 0; j < 4; ++j) {
      int col = colBase + wc * 64 + j * 16 + fc;
      float bv = bias[col];
#pragma unroll
      for (int r = 0; r < 4; ++r) {
        int row = rowBase + wr * 64 + i * 16 + rq * 4 + r;
        if (row < M) storeC(C, (size_t)row * ldc + col, acc[i][j][r] + bv);
      }
    }
  }
}

// ---------------------------------------------------------------------------
// Prep: x -> bf16; weights -> transposed bf16 pair-layouts + bias arrays.
// W1t[p][1024][256]: n -> hh=n>>9, sel=(n>>7)&3 (q,k,v,s), c=(2p+hh)*128+(n&127)
// W2t[p][768][512]:  n -> hh=n/384, r=n%384, sel=r>>7 (q,k,v), c=(2p+hh)*128+(r&127)
// Ws2t[128][512]
// ---------------------------------------------------------------------------
__global__ void cvt_bf16_kernel(const float* __restrict__ in, ushort_t* __restrict__ out, int n4) {
  int i = blockIdx.x * blockDim.x + threadIdx.x;
  if (i >= n4) return;
  float4 f = *(const float4*)(in + (size_t)i * 4);
  uint_t lo = (uint_t)f2bf(f.x) | ((uint_t)f2bf(f.y) << 16);
  uint_t hi = (uint_t)f2bf(f.z) | ((uint_t)f2bf(f.w) << 16);
  ((uint2*)out)[i] = make_uint2(lo, hi);
}

#define L1_W   (2 * 1024 * FEAT)
#define L2_W   (2 * 768 * HID)
#define SK_W   (CH * HID)

__global__ void prep_weights(
    const float* __restrict__ Wq1, const float* __restrict__ Wk1,
    const float* __restrict__ Wv1, const float* __restrict__ Ws1,
    const float* __restrict__ bq1, const float* __restrict__ bk1,
    const float* __restrict__ bv1, const float* __restrict__ bs1,
    const float* __restrict__ Wq2, const float* __restrict__ Wk2,
    const float* __restrict__ Wv2,
    const float* __restrict__ bq2, const float* __restrict__ bk2,
    const float* __restrict__ bv2,
    const float* __restrict__ Ws2,
    ushort_t* __restrict__ W1t, float* __restrict__ Bh1,
    ushort_t* __restrict__ W2t, float* __restrict__ Bh2,
    ushort_t* __restrict__ Ws2t) {
  int idx = blockIdx.x * blockDim.x + threadIdx.x;
  if (idx < L1_W) {
    int k = idx & (FEAT - 1);
    int n = (idx >> 8) & 1023;
    int p = idx >> 18;
    int hh = n >> 9, sel = (n >> 7) & 3;
    int c = (2 * p + hh) * CH + (n & (CH - 1));
    const float* W = sel == 0 ? Wq1 : sel == 1 ? Wk1 : sel == 2 ? Wv1 : Ws1;
    W1t[idx] = f2bf(W[(size_t)k * HID + c]);
    if (k == 0) {
      const float* b = sel == 0 ? bq1 : sel == 1 ? bk1 : sel == 2 ? bv1 : bs1;
      Bh1[p * 1024 + n] = b[c];
    }
    return;
  }
  idx -= L1_W;
  if (idx < L2_W) {
    int k = idx & (HID - 1);
    int t = idx >> 9;          // [0, 1536)
    int n = t % 768, p = t / 768;
    int hh = n / 384, r = n % 384, sel = r >> 7;
    int c = (2 * p + hh) * CH + (r & (CH - 1));
    const float* W = sel == 0 ? Wq2 : sel == 1 ? Wk2 : Wv2;
    W2t[idx] = f2bf(W[(size_t)k * HID + c]);
    if (k == 0) {
      const float* b = sel == 0 ? bq2 : sel == 1 ? bk2 : bv2;
      Bh2[p * 768 + n] = b[c];
    }
    return;
  }
  idx -= L2_W;
  if (idx < SK_W) {
    int k = idx & (HID - 1);
    int n = idx >> 9;
    Ws2t[idx] = f2bf(Ws2[(size_t)k * CH + n]);
  }
}

// ---------------------------------------------------------------------------
// CSR build: zero -> hist+bounds -> alloc (wave atomic) -> scatter
// ---------------------------------------------------------------------------
__global__ void zero_kernel(int* __restrict__ deg, int* __restrict__ counter,
                            int* __restrict__ gstart, int* __restrict__ gend,
                            float* __restrict__ pooled) {
  int i = blockIdx.x * blockDim.x + threadIdx.x;
  if (i < N_NODES) deg[i] = 0;
  if (i < NGRAPH) { gstart[i] = 0; gend[i] = 0; }
  if (i < NGRAPH * CH) pooled[i] = 0.f;
  if (i == 0) counter[0] = 0;
}

__global__ void hist_bounds_kernel(const int* __restrict__ dst, int* __restrict__ deg,
                                   const int* __restrict__ batch,
                                   int* __restrict__ gstart, int* __restrict__ gend) {
  int t = blockIdx.x * blockDim.x + threadIdx.x;
  if (t < EDGES) atomicAdd(&deg[dst[t]], 1);
  if (t < N_NODES) {
    int b = batch[t];
    if (t == 0 || batch[t - 1] != b) gstart[b] = t;
    if (t == N_NODES - 1 || batch[t + 1] != b) gend[b] = t + 1;
  }
}

// Unordered segment allocation: start[i] = wave-prefix + one atomic per wave.
__global__ void alloc_kernel(const int* __restrict__ deg, int* __restrict__ counter,
                             int* __restrict__ start, int* __restrict__ cursor) {
  int i = blockIdx.x * blockDim.x + threadIdx.x;
  int lane = threadIdx.x & 63;
  int v = (i < N_NODES) ? deg[i] : 0;
  int sum = v;
#pragma unroll
  for (int off = 1; off < 64; off <<= 1) {
    int t = __shfl_up(sum, off);
    if (lane >= off) sum += t;
  }
  int excl = sum - v;
  int waveTot = __shfl(sum, 63);
  int base = 0;
  if (lane == 63) base = atomicAdd(counter, waveTot);
  base = __shfl(base, 63);
  if (i < N_NODES) {
    start[i] = base + excl;
    cursor[i] = base + excl;
  }
}

__global__ void scatter_kernel(const int* __restrict__ src, const int* __restrict__ dst,
                               int* __restrict__ cursor, int* __restrict__ csr) {
  int e = blockIdx.x * blockDim.x + threadIdx.x;
  if (e < EDGES) {
    int pos = atomicAdd(&cursor[dst[e]], 1);
    csr[pos] = src[e];
  }
}

// ---------------------------------------------------------------------------
// Attention: one wave per (node, head). Online softmax over in-edges.
// ---------------------------------------------------------------------------
__device__ __forceinline__ void attn_loop(
    const ushort_t* __restrict__ QKV, int stride, int qOff,
    int i, int lane, const int* __restrict__ start, const int* __restrict__ deg,
    const int* __restrict__ csr, float& a0, float& a1, float& ssum) {
  const ushort_t* qp = QKV + (size_t)i * stride + qOff;
  uint_t qw = *(const uint_t*)(qp + 2 * lane);
  float q0 = bf2f((ushort_t)qw), q1 = bf2f((ushort_t)(qw >> 16));
  int beg = start[i], end = beg + deg[i];
  float m = -INFINITY;
  ssum = 0.f; a0 = 0.f; a1 = 0.f;
  for (int e = beg; e < end; ++e) {
    int j = csr[e];
    const ushort_t* jp = QKV + (size_t)j * stride + qOff;
    uint_t kw = *(const uint_t*)(jp + CH + 2 * lane);
    uint_t vw = *(const uint_t*)(jp + 2 * CH + 2 * lane);
    float p = q0 * bf2f((ushort_t)kw) + q1 * bf2f((ushort_t)(kw >> 16));
#pragma unroll
    for (int off = 32; off > 0; off >>= 1) p += __shfl_xor(p, off);
    float alpha = p * 0.08838834764831845f;  // 1/sqrt(128)
    float mn = fmaxf(m, alpha);
    float sc = expf(m - mn);    // first iter: exp(-inf)=0
    float w = expf(alpha - mn);
    ssum = ssum * sc + w;
    a0 = a0 * sc + w * bf2f((ushort_t)vw);
    a1 = a1 * sc + w * bf2f((ushort_t)(vw >> 16));
    m = mn;
  }
}

// layer 1 (pair p, hh = blockIdx.y): QKVS2 stride 1024, q at hh*512,
// k/v/s at +128/+256/+384; fused skip-add + ELU; write H1b col (2p+hh)*128.
__global__ __launch_bounds__(256) void attn1_kernel(
    const ushort_t* __restrict__ QKVS2, const int* __restrict__ start,
    const int* __restrict__ deg, const int* __restrict__ csr,
    ushort_t* __restrict__ H1b, int p) {
  int wid = threadIdx.x >> 6, lane = threadIdx.x & 63;
  int i = blockIdx.x * 4 + wid;
  if (i >= N_NODES) return;
  int hh = blockIdx.y;
  float a0, a1, ssum;
  attn_loop(QKVS2, 1024, hh * 512, i, lane, start, deg, csr, a0, a1, ssum);
  float inv = 1.f / (ssum + 1e-16f);
  uint_t sw = *(const uint_t*)(QKVS2 + (size_t)i * 1024 + hh * 512 + 3 * CH + 2 * lane);
  float o0 = a0 * inv + bf2f((ushort_t)sw);
  float o1 = a1 * inv + bf2f((ushort_t)(sw >> 16));
  o0 = o0 > 0.f ? o0 : expm1f(o0);
  o1 = o1 > 0.f ? o1 : expm1f(o1);
  uint_t ow = (uint_t)f2bf(o0) | ((uint_t)f2bf(o1) << 16);
  *(uint_t*)(H1b + (size_t)i * HID + (2 * p + hh) * CH + 2 * lane) = ow;
}

// layer 2 (pair p, hh = blockIdx.y): QKV2 stride 768, q at hh*384;
// accumulate 0.25*msg into fp32 S2 (pre-filled with skip).
__global__ __launch_bounds__(256) void attn2_kernel(
    const ushort_t* __restrict__ QKV2, const int* __restrict__ start,
    const int* __restrict__ deg, const int* __restrict__ csr,
    float* __restrict__ S2) {
  int wid = threadIdx.x >> 6, lane = threadIdx.x & 63;
  int i = blockIdx.x * 4 + wid;
  if (i >= N_NODES) return;
  int hh = blockIdx.y;
  float a0, a1, ssum;
  attn_loop(QKV2, 768, hh * 384, i, lane, start, deg, csr, a0, a1, ssum);
  float inv = 0.25f / (ssum + 1e-16f);
  float2* p2 = (float2*)(S2 + (size_t)i * CH) + lane;
  float2 v = *p2;
  v.x += a0 * inv;
  v.y += a1 * inv;
  *p2 = v;
}

// ---------------------------------------------------------------------------
// Pool: node-parallel ELU + atomic accumulate into pooled[G][CH].
// ---------------------------------------------------------------------------
__global__ void pool_accum(const float* __restrict__ S2, const int* __restrict__ batch,
                           float* __restrict__ pooled) {
  int idx = blockIdx.x * blockDim.x + threadIdx.x;
  if (idx >= N_NODES * CH) return;
  int i = idx >> 7, c = idx & (CH - 1);
  float v = S2[idx];
  v = v > 0.f ? v : expm1f(v);
  atomicAdd(&pooled[batch[i] * CH + c], v);
}

__global__ __launch_bounds__(128) void cls_kernel(
    const float* __restrict__ pooled, const int* __restrict__ gstart,
    const int* __restrict__ gend, const float* __restrict__ Wfc,
    const float* __restrict__ bfc, float* __restrict__ out) {
  int g = blockIdx.x;
  int t = threadIdx.x;
  float cnt = fmaxf((float)(gend[g] - gstart[g]), 1.f);
  __shared__ float red[CH];
  __shared__ float logits[NCLS];
  float pv = pooled[g * CH + t] / cnt;
  for (int c = 0; c < NCLS; ++c) {
    __syncthreads();
    red[t] = pv * Wfc[t * NCLS + c];
    __syncthreads();
    for (int off = 64; off > 0; off >>= 1) {
      if (t < off) red[t] += red[t + off];
      __syncthreads();
    }
    if (t == 0) logits[c] = red[0] + bfc[c];
  }
  __syncthreads();
  if (t == 0) {
    float mx = -INFINITY;
    for (int c = 0; c < NCLS; ++c) mx = fmaxf(mx, logits[c]);
    float se = 0.f;
    for (int c = 0; c < NCLS; ++c) se += expf(logits[c] - mx);
    float ls = mx + logf(se);
    for (int c = 0; c < NCLS; ++c) out[g * NCLS + c] = logits[c] - ls;
  }
}

// ---------------------------------------------------------------------------
extern "C" void kernel_launch(void* const* d_in, const int* in_sizes, int n_in,
                              void* d_out, int out_size, void* d_ws, size_t ws_size,
                              hipStream_t stream) {
  const float* x    = (const float*)d_in[0];
  const int*   ei   = (const int*)d_in[1];
  const int*   batch= (const int*)d_in[2];
  const float* Wq1 = (const float*)d_in[3];  const float* bq1 = (const float*)d_in[4];
  const float* Wk1 = (const float*)d_in[5];  const float* bk1 = (const float*)d_in[6];
  const float* Wv1 = (const float*)d_in[7];  const float* bv1 = (const float*)d_in[8];
  const float* Ws1 = (const float*)d_in[9];  const float* bs1 = (const float*)d_in[10];
  const float* Wq2 = (const float*)d_in[11]; const float* bq2 = (const float*)d_in[12];
  const float* Wk2 = (const float*)d_in[13]; const float* bk2 = (const float*)d_in[14];
  const float* Wv2 = (const float*)d_in[15]; const float* bv2 = (const float*)d_in[16];
  const float* Ws2 = (const float*)d_in[17]; const float* bs2 = (const float*)d_in[18];
  const float* Wfc = (const float*)d_in[19]; const float* bfc = (const float*)d_in[20];
  float* out = (float*)d_out;

  // Workspace (~184 MB)
  ushort_t* xb   = (ushort_t*)d_ws;                    // N x 256 bf16
  ushort_t* BIG  = xb + (size_t)N_NODES * FEAT;        // N x 1024 bf16
  // layer1 view: QKVS2 = BIG (stride 1024: [q|k|v|s] x 2 heads)
  // layer2 view: QKV2 = BIG (stride 768), S2 = fp32 after it
  ushort_t* QKV2 = BIG;
  float*    S2   = (float*)(BIG + (size_t)N_NODES * 768);  // N x 128 fp32
  ushort_t* H1b  = BIG + (size_t)N_NODES * 1024;       // N x 512 bf16
  ushort_t* W1t  = H1b + (size_t)N_NODES * HID;        // 2*1024*256
  float*    Bh1  = (float*)(W1t + L1_W);               // 2*1024
  ushort_t* W2t  = (ushort_t*)(Bh1 + 2 * 1024);        // 2*768*512
  float*    Bh2  = (float*)(W2t + L2_W);               // 2*768
  ushort_t* Ws2t = (ushort_t*)(Bh2 + 2 * 768);         // 128*512
  float*    pooled = (float*)(Ws2t + SK_W);            // 256*128
  int* deg    = (int*)(pooled + NGRAPH * CH);
  int* start  = deg + N_NODES;
  int* cursor = start + N_NODES;
  int* csr    = cursor + N_NODES;
  int* gstart = csr + EDGES;
  int* gend   = gstart + NGRAPH;
  int* counter= gend + NGRAPH;

  const int* srcp = ei;
  const int* dstp = ei + EDGES;

  // ---- prep ----
  cvt_bf16_kernel<<<(N_NODES * FEAT / 4 + 255) / 256, 256, 0, stream>>>(x, xb, N_NODES * FEAT / 4);
  prep_weights<<<(L1_W + L2_W + SK_W + 255) / 256, 256, 0, stream>>>(
      Wq1, Wk1, Wv1, Ws1, bq1, bk1, bv1, bs1,
      Wq2, Wk2, Wv2, bq2, bk2, bv2, Ws2, W1t, Bh1, W2t, Bh2, Ws2t);

  // ---- CSR build ----
  zero_kernel<<<(N_NODES + 255) / 256, 256, 0, stream>>>(deg, counter, gstart, gend, pooled);
  hist_bounds_kernel<<<(EDGES + 255) / 256, 256, 0, stream>>>(dstp, deg, batch, gstart, gend);
  alloc_kernel<<<(N_NODES + 255) / 256, 256, 0, stream>>>(deg, counter, start, cursor);
  scatter_kernel<<<(EDGES + 255) / 256, 256, 0, stream>>>(srcp, dstp, cursor, csr);

  const int gx = (N_NODES + 127) / 128;  // 391
  const int ga = (N_NODES + 3) / 4;      // 12500

  // ---- layer 1: per head-pair, GEMM (1024 cols) + attention (fused skip+ELU) ----
  for (int p = 0; p < 2; ++p) {
    gemm_bt<ushort_t><<<dim3(gx, 8), 256, 0, stream>>>(
        xb, W1t + (size_t)p * 1024 * FEAT, Bh1 + p * 1024, BIG, 1024, N_NODES, FEAT);
    attn1_kernel<<<dim3(ga, 2), 256, 0, stream>>>(BIG, start, deg, csr, H1b, p);
  }

  // ---- layer 2: skip into fp32 S2, then per-pair GEMM (768 cols) + attention ----
  gemm_bt<float><<<dim3(gx, 1), 256, 0, stream>>>(
      H1b, Ws2t, bs2, S2, CH, N_NODES, HID);
  for (int p = 0; p < 2; ++p) {
    gemm_bt<ushort_t><<<dim3(gx, 6), 256, 0, stream>>>(
        H1b, W2t + (size_t)p * 768 * HID, Bh2 + p * 768, QKV2, 768, N_NODES, HID);
    attn2_kernel<<<dim3(ga, 2), 256, 0, stream>>>(QKV2, start, deg, csr, S2);
  }

  // ---- pool (fused ELU) + classify ----
  pool_accum<<<(N_NODES * CH + 255) / 256, 256, 0, stream>>>(S2, batch, pooled);
  cls_kernel<<<NGRAPH, CH, 0, stream>>>(pooled, gstart, gend, Wfc, bfc, out);
}

// Round 5
// 764.371 us; speedup vs baseline: 4.2208x; 1.1311x over previous
//
#include <hip/hip_runtime.h>
#include <math.h>
#include <stdint.h>

#define N_NODES 50000
#define FEAT    256
#define EDGES   200000
#define HEADS   4
#define CH      128
#define HID     512   // HEADS*CH
#define NGRAPH  256
#define NCLS    10

typedef unsigned short ushort_t;
typedef unsigned int uint_t;
typedef __attribute__((ext_vector_type(8))) short bf16x8;
typedef __attribute__((ext_vector_type(4))) float f32x4;

__device__ __forceinline__ ushort_t f2bf(float f) {  // round-to-nearest-even
  uint_t u = __float_as_uint(f);
  u += 0x7FFF + ((u >> 16) & 1);
  return (ushort_t)(u >> 16);
}
__device__ __forceinline__ float bf2f(ushort_t h) {
  return __uint_as_float(((uint_t)h) << 16);
}
__device__ __forceinline__ void unpack8(uint4 w, float* f) {
  f[0] = bf2f((ushort_t)w.x); f[1] = bf2f((ushort_t)(w.x >> 16));
  f[2] = bf2f((ushort_t)w.y); f[3] = bf2f((ushort_t)(w.y >> 16));
  f[4] = bf2f((ushort_t)w.z); f[5] = bf2f((ushort_t)(w.z >> 16));
  f[6] = bf2f((ushort_t)w.w); f[7] = bf2f((ushort_t)(w.w >> 16));
}

// ---------------------------------------------------------------------------
// bf16 MFMA GEMM (m97 structure): C[M,N] = A[M,K] @ Bt[N,K]^T + bias
// 128x128 tile, BK=32, 256 threads (4 waves, 2x2), 4x4 16x16x32 tiles/wave.
// XOR-chunk-swizzled LDS; global_load_lds width=16 staging.
// ---------------------------------------------------------------------------
__device__ __forceinline__ void storeC(float* C, size_t idx, float v) { C[idx] = v; }
__device__ __forceinline__ void storeC(ushort_t* C, size_t idx, float v) { C[idx] = f2bf(v); }

template <typename CT>
__global__ __launch_bounds__(256) void gemm_bt(
    const ushort_t* __restrict__ A, const ushort_t* __restrict__ Bt,
    const float* __restrict__ bias, CT* __restrict__ C, int ldc,
    int M, int K) {
  __shared__ __align__(16) ushort_t sA[128 * 32];
  __shared__ __align__(16) ushort_t sB[128 * 32];
  const int tid = threadIdx.x;
  const int lane = tid & 63, wave = tid >> 6;
  const int wr = wave >> 1, wc = wave & 1;
  const int rowBase = blockIdx.x * 128, colBase = blockIdx.y * 128;
  f32x4 acc[4][4] = {};

  for (int k0 = 0; k0 < K; k0 += 32) {
#pragma unroll
    for (int j = 0; j < 2; ++j) {
      int rl = j * 64 + (tid >> 2);       // local row/col 0..127
      int slot = tid & 3;
      int cg = slot ^ (rl & 3);           // swizzle chunk
      {
        int row = rowBase + rl;
        row = row < M ? row : M - 1;      // clamp tail (epilogue guards writes)
        const ushort_t* gp = A + (size_t)row * K + k0 + cg * 8;
        __builtin_amdgcn_global_load_lds(
            (const __attribute__((address_space(1))) uint_t*)gp,
            (__attribute__((address_space(3))) uint_t*)(sA + j * 2048 + tid * 8),
            16, 0, 0);
      }
      {
        int n = colBase + rl;             // N multiple of 128 always
        const ushort_t* gp = Bt + (size_t)n * K + k0 + cg * 8;
        __builtin_amdgcn_global_load_lds(
            (const __attribute__((address_space(1))) uint_t*)gp,
            (__attribute__((address_space(3))) uint_t*)(sB + j * 2048 + tid * 8),
            16, 0, 0);
      }
    }
    __syncthreads();
    const int fr = lane & 15, c0 = lane >> 4;
    bf16x8 af[4], bfr[4];
#pragma unroll
    for (int i = 0; i < 4; ++i) {
      int r = wr * 64 + i * 16 + fr;
      af[i] = *(const bf16x8*)(sA + r * 32 + ((c0 ^ (r & 3)) * 8));
      int n = wc * 64 + i * 16 + fr;
      bfr[i] = *(const bf16x8*)(sB + n * 32 + ((c0 ^ (n & 3)) * 8));
    }
#pragma unroll
    for (int i = 0; i < 4; ++i)
#pragma unroll
      for (int j = 0; j < 4; ++j)
        acc[i][j] = __builtin_amdgcn_mfma_f32_16x16x32_bf16(af[i], bfr[j], acc[i][j], 0, 0, 0);
    __syncthreads();
  }

  const int fc = lane & 15, rq = lane >> 4;
#pragma unroll
  for (int i = 0; i < 4; ++i) {
#pragma unroll
    for (int j = 0; j < 4; ++j) {
      int col = colBase + wc * 64 + j * 16 + fc;
      float bv = bias[col];
#pragma unroll
      for (int r = 0; r < 4; ++r) {
        int row = rowBase + wr * 64 + i * 16 + rq * 4 + r;
        if (row < M) storeC(C, (size_t)row * ldc + col, acc[i][j][r] + bv);
      }
    }
  }
}

// ---------------------------------------------------------------------------
// Prep: x -> bf16; weights -> transposed bf16 layouts + bias arrays.
// W1t[p][1024][256]: n -> hh=n>>9, sel=(n>>7)&3 (q,k,v,s), c=(2p+hh)*128+(n&127)
// W2t[1664][512]: n<768: heads 0,1 (q|k|v each 128); n in [768,896): skip cols;
//                 n>=896: heads 2,3.
// ---------------------------------------------------------------------------
__global__ void cvt_bf16_kernel(const float* __restrict__ in, ushort_t* __restrict__ out, int n4) {
  int i = blockIdx.x * blockDim.x + threadIdx.x;
  if (i >= n4) return;
  float4 f = *(const float4*)(in + (size_t)i * 4);
  uint_t lo = (uint_t)f2bf(f.x) | ((uint_t)f2bf(f.y) << 16);
  uint_t hi = (uint_t)f2bf(f.z) | ((uint_t)f2bf(f.w) << 16);
  ((uint2*)out)[i] = make_uint2(lo, hi);
}

#define L1_W   (2 * 1024 * FEAT)
#define L2_W   (1664 * HID)

__global__ void prep_weights(
    const float* __restrict__ Wq1, const float* __restrict__ Wk1,
    const float* __restrict__ Wv1, const float* __restrict__ Ws1,
    const float* __restrict__ bq1, const float* __restrict__ bk1,
    const float* __restrict__ bv1, const float* __restrict__ bs1,
    const float* __restrict__ Wq2, const float* __restrict__ Wk2,
    const float* __restrict__ Wv2,
    const float* __restrict__ bq2, const float* __restrict__ bk2,
    const float* __restrict__ bv2,
    const float* __restrict__ Ws2, const float* __restrict__ bs2,
    ushort_t* __restrict__ W1t, float* __restrict__ Bh1,
    ushort_t* __restrict__ W2t, float* __restrict__ Bh2) {
  int idx = blockIdx.x * blockDim.x + threadIdx.x;
  if (idx < L1_W) {
    int k = idx & (FEAT - 1);
    int n = (idx >> 8) & 1023;
    int p = idx >> 18;
    int hh = n >> 9, sel = (n >> 7) & 3;
    int c = (2 * p + hh) * CH + (n & (CH - 1));
    const float* W = sel == 0 ? Wq1 : sel == 1 ? Wk1 : sel == 2 ? Wv1 : Ws1;
    W1t[idx] = f2bf(W[(size_t)k * HID + c]);
    if (k == 0) {
      const float* b = sel == 0 ? bq1 : sel == 1 ? bk1 : sel == 2 ? bv1 : bs1;
      Bh1[p * 1024 + n] = b[c];
    }
    return;
  }
  idx -= L1_W;
  if (idx < L2_W) {
    int k = idx & (HID - 1);
    int n = idx >> 9;          // 0..1663
    if (n < 768 || n >= 896) {
      int n2 = (n < 768) ? n : n - 896;
      int headBase = (n < 768) ? 0 : 2;
      int hh = headBase + n2 / 384, r = n2 % 384, sel = r >> 7;
      int c = hh * CH + (r & (CH - 1));
      const float* W = sel == 0 ? Wq2 : sel == 1 ? Wk2 : Wv2;
      W2t[idx] = f2bf(W[(size_t)k * HID + c]);
      if (k == 0) {
        const float* b = sel == 0 ? bq2 : sel == 1 ? bk2 : bv2;
        Bh2[n] = b[c];
      }
    } else {
      int cc = n - 768;
      W2t[idx] = f2bf(Ws2[(size_t)k * CH + cc]);
      if (k == 0) Bh2[n] = bs2[cc];
    }
  }
}

// ---------------------------------------------------------------------------
// CSR build: zero -> hist+bounds -> alloc (wave atomic) -> scatter
// ---------------------------------------------------------------------------
__global__ void zero_kernel(int* __restrict__ deg, int* __restrict__ counter,
                            int* __restrict__ gstart, int* __restrict__ gend,
                            float* __restrict__ pooled) {
  int i = blockIdx.x * blockDim.x + threadIdx.x;
  if (i < N_NODES) deg[i] = 0;
  if (i < NGRAPH) { gstart[i] = 0; gend[i] = 0; }
  if (i < NGRAPH * CH) pooled[i] = 0.f;
  if (i == 0) counter[0] = 0;
}

__global__ void hist_bounds_kernel(const int* __restrict__ dst, int* __restrict__ deg,
                                   const int* __restrict__ batch,
                                   int* __restrict__ gstart, int* __restrict__ gend) {
  int t = blockIdx.x * blockDim.x + threadIdx.x;
  if (t < EDGES) atomicAdd(&deg[dst[t]], 1);
  if (t < N_NODES) {
    int b = batch[t];
    if (t == 0 || batch[t - 1] != b) gstart[b] = t;
    if (t == N_NODES - 1 || batch[t + 1] != b) gend[b] = t + 1;
  }
}

// Unordered segment allocation: start[i] = wave-prefix + one atomic per wave.
__global__ void alloc_kernel(const int* __restrict__ deg, int* __restrict__ counter,
                             int* __restrict__ start, int* __restrict__ cursor) {
  int i = blockIdx.x * blockDim.x + threadIdx.x;
  int lane = threadIdx.x & 63;
  int v = (i < N_NODES) ? deg[i] : 0;
  int sum = v;
#pragma unroll
  for (int off = 1; off < 64; off <<= 1) {
    int t = __shfl_up(sum, off);
    if (lane >= off) sum += t;
  }
  int excl = sum - v;
  int waveTot = __shfl(sum, 63);
  int base = 0;
  if (lane == 63) base = atomicAdd(counter, waveTot);
  base = __shfl(base, 63);
  if (i < N_NODES) {
    start[i] = base + excl;
    cursor[i] = base + excl;
  }
}

__global__ void scatter_kernel(const int* __restrict__ src, const int* __restrict__ dst,
                               int* __restrict__ cursor, int* __restrict__ csr) {
  int e = blockIdx.x * blockDim.x + threadIdx.x;
  if (e < EDGES) {
    int pos = atomicAdd(&cursor[dst[e]], 1);
    csr[pos] = src[e];
  }
}

// ---------------------------------------------------------------------------
// Attention core: one wave per (node, head). 4 x 16-lane groups process 4
// edges in parallel (8 channels/lane, uint4 loads); per-group online-softmax
// states merged at the end via 2 butterfly rounds over lane bits 4,5.
// ---------------------------------------------------------------------------
__device__ __forceinline__ void attn_node_head(
    const ushort_t* __restrict__ buf, int stride, int off,
    int i, int li, int g, int beg, int end, const int* __restrict__ csr,
    float* a, float& sout) {
  float q[8];
  unpack8(*(const uint4*)(buf + (size_t)i * stride + off + li * 8), q);
  float m = -1e30f, s = 0.f;
#pragma unroll
  for (int c = 0; c < 8; ++c) a[c] = 0.f;
  for (int e0 = beg; e0 < end; e0 += 4) {
    int eg = e0 + g;
    bool valid = eg < end;
    int j = csr[valid ? eg : beg];
    const ushort_t* jp = buf + (size_t)j * stride + off;
    uint4 kw = *(const uint4*)(jp + CH + li * 8);
    uint4 vw = *(const uint4*)(jp + 2 * CH + li * 8);
    float kf[8]; unpack8(kw, kf);
    float p = q[0] * kf[0] + q[1] * kf[1] + q[2] * kf[2] + q[3] * kf[3] +
              q[4] * kf[4] + q[5] * kf[5] + q[6] * kf[6] + q[7] * kf[7];
    p += __shfl_xor(p, 1);
    p += __shfl_xor(p, 2);
    p += __shfl_xor(p, 4);
    p += __shfl_xor(p, 8);
    float alpha = valid ? p * 0.08838834764831845f : -1e30f;  // 1/sqrt(128)
    float mn = fmaxf(m, alpha);
    float sc = expf(m - mn);               // finite args: no NaN
    float w = valid ? expf(alpha - mn) : 0.f;
    float vf[8]; unpack8(vw, vf);
    s = s * sc + w;
#pragma unroll
    for (int c = 0; c < 8; ++c) a[c] = a[c] * sc + w * vf[c];
    m = mn;
  }
  // merge the 4 group states (lane bits 4 and 5)
#pragma unroll
  for (int ox = 16; ox <= 32; ox <<= 1) {
    float mo = __shfl_xor(m, ox);
    float so = __shfl_xor(s, ox);
    float mn = fmaxf(m, mo);
    float sc1 = expf(m - mn), sc2 = expf(mo - mn);
    s = s * sc1 + so * sc2;
#pragma unroll
    for (int c = 0; c < 8; ++c) {
      float ao = __shfl_xor(a[c], ox);
      a[c] = a[c] * sc1 + ao * sc2;
    }
    m = mn;
  }
  sout = s;
}

// layer 1 (pair p, hh = blockIdx.y): stride 1024, q at hh*512, k/v/s at
// +128/+256/+384; fused skip-add + ELU; write H1b col (2p+hh)*128.
__global__ __launch_bounds__(256) void attn1_kernel(
    const ushort_t* __restrict__ QKVS2, const int* __restrict__ start,
    const int* __restrict__ deg, const int* __restrict__ csr,
    ushort_t* __restrict__ H1b, int p) {
  int wave = threadIdx.x >> 6, lane = threadIdx.x & 63;
  int li = lane & 15, g = lane >> 4;
  int i = blockIdx.x * 4 + wave;
  if (i >= N_NODES) return;
  int hh = blockIdx.y;
  int beg = start[i], end = beg + deg[i];
  float a[8], s;
  attn_node_head(QKVS2, 1024, hh * 512, i, li, g, beg, end, csr, a, s);
  if (g != 0) return;
  float inv = 1.f / (s + 1e-16f);
  float sk[8];
  unpack8(*(const uint4*)(QKVS2 + (size_t)i * 1024 + hh * 512 + 384 + li * 8), sk);
  uint4 ow;
  uint_t* op = (uint_t*)&ow;
#pragma unroll
  for (int c = 0; c < 4; ++c) {
    float o0 = a[2 * c] * inv + sk[2 * c];
    float o1 = a[2 * c + 1] * inv + sk[2 * c + 1];
    o0 = o0 > 0.f ? o0 : expm1f(o0);
    o1 = o1 > 0.f ? o1 : expm1f(o1);
    op[c] = (uint_t)f2bf(o0) | ((uint_t)f2bf(o1) << 16);
  }
  *(uint4*)(H1b + (size_t)i * HID + (2 * p + hh) * CH + li * 8) = ow;
}

// layer 2: one wave per node, loops 2 heads (offsets 0, 384; stride 1024).
// first=1: S2 = skip(bf16 at col 768) + 0.25*(m0+m1); else S2 += ...
__global__ __launch_bounds__(256) void attn2_kernel(
    const ushort_t* __restrict__ buf, const int* __restrict__ start,
    const int* __restrict__ deg, const int* __restrict__ csr,
    float* __restrict__ S2, int first) {
  int wave = threadIdx.x >> 6, lane = threadIdx.x & 63;
  int li = lane & 15, g = lane >> 4;
  int i = blockIdx.x * 4 + wave;
  if (i >= N_NODES) return;
  int beg = start[i], end = beg + deg[i];
  float msum[8] = {};
  for (int hh = 0; hh < 2; ++hh) {
    float a[8], s;
    attn_node_head(buf, 1024, hh * 384, i, li, g, beg, end, csr, a, s);
    float inv = 0.25f / (s + 1e-16f);
#pragma unroll
    for (int c = 0; c < 8; ++c) msum[c] += a[c] * inv;
  }
  if (g != 0) return;
  float* sp = S2 + (size_t)i * CH + li * 8;
  if (first) {
    float sk[8];
    unpack8(*(const uint4*)(buf + (size_t)i * 1024 + 768 + li * 8), sk);
#pragma unroll
    for (int c = 0; c < 8; ++c) sp[c] = sk[c] + msum[c];
  } else {
#pragma unroll
    for (int c = 0; c < 8; ++c) sp[c] += msum[c];
  }
}

// ---------------------------------------------------------------------------
// Pool: node-parallel ELU + atomic accumulate into pooled[G][CH].
// ---------------------------------------------------------------------------
__global__ void pool_accum(const float* __restrict__ S2, const int* __restrict__ batch,
                           float* __restrict__ pooled) {
  int idx = blockIdx.x * blockDim.x + threadIdx.x;
  if (idx >= N_NODES * CH) return;
  int i = idx >> 7, c = idx & (CH - 1);
  float v = S2[idx];
  v = v > 0.f ? v : expm1f(v);
  atomicAdd(&pooled[batch[i] * CH + c], v);
}

__global__ __launch_bounds__(128) void cls_kernel(
    const float* __restrict__ pooled, const int* __restrict__ gstart,
    const int* __restrict__ gend, const float* __restrict__ Wfc,
    const float* __restrict__ bfc, float* __restrict__ out) {
  int g = blockIdx.x;
  int t = threadIdx.x;
  float cnt = fmaxf((float)(gend[g] - gstart[g]), 1.f);
  __shared__ float red[CH];
  __shared__ float logits[NCLS];
  float pv = pooled[g * CH + t] / cnt;
  for (int c = 0; c < NCLS; ++c) {
    __syncthreads();
    red[t] = pv * Wfc[t * NCLS + c];
    __syncthreads();
    for (int off = 64; off > 0; off >>= 1) {
      if (t < off) red[t] += red[t + off];
      __syncthreads();
    }
    if (t == 0) logits[c] = red[0] + bfc[c];
  }
  __syncthreads();
  if (t == 0) {
    float mx = -INFINITY;
    for (int c = 0; c < NCLS; ++c) mx = fmaxf(mx, logits[c]);
    float se = 0.f;
    for (int c = 0; c < NCLS; ++c) se += expf(logits[c] - mx);
    float ls = mx + logf(se);
    for (int c = 0; c < NCLS; ++c) out[g * NCLS + c] = logits[c] - ls;
  }
}

// ---------------------------------------------------------------------------
extern "C" void kernel_launch(void* const* d_in, const int* in_sizes, int n_in,
                              void* d_out, int out_size, void* d_ws, size_t ws_size,
                              hipStream_t stream) {
  const float* x    = (const float*)d_in[0];
  const int*   ei   = (const int*)d_in[1];
  const int*   batch= (const int*)d_in[2];
  const float* Wq1 = (const float*)d_in[3];  const float* bq1 = (const float*)d_in[4];
  const float* Wk1 = (const float*)d_in[5];  const float* bk1 = (const float*)d_in[6];
  const float* Wv1 = (const float*)d_in[7];  const float* bv1 = (const float*)d_in[8];
  const float* Ws1 = (const float*)d_in[9];  const float* bs1 = (const float*)d_in[10];
  const float* Wq2 = (const float*)d_in[11]; const float* bq2 = (const float*)d_in[12];
  const float* Wk2 = (const float*)d_in[13]; const float* bk2 = (const float*)d_in[14];
  const float* Wv2 = (const float*)d_in[15]; const float* bv2 = (const float*)d_in[16];
  const float* Ws2 = (const float*)d_in[17]; const float* bs2 = (const float*)d_in[18];
  const float* Wfc = (const float*)d_in[19]; const float* bfc = (const float*)d_in[20];
  float* out = (float*)d_out;

  // Workspace (~183 MB). S2 (fp32 N*128 = 25.6MB) aliases xb (dead after L1 GEMMs).
  ushort_t* xb   = (ushort_t*)d_ws;                    // N x 256 bf16
  float*    S2   = (float*)d_ws;                       // N x 128 fp32 (aliases xb)
  ushort_t* BIG  = xb + (size_t)N_NODES * FEAT;        // N x 1024 bf16
  ushort_t* H1b  = BIG + (size_t)N_NODES * 1024;       // N x 512 bf16
  ushort_t* W1t  = H1b + (size_t)N_NODES * HID;        // 2*1024*256
  float*    Bh1  = (float*)(W1t + L1_W);               // 2*1024
  ushort_t* W2t  = (ushort_t*)(Bh1 + 2 * 1024);        // 1664*512
  float*    Bh2  = (float*)(W2t + L2_W);               // 1664
  float*    pooled = Bh2 + 1664;                       // 256*128
  int* deg    = (int*)(pooled + NGRAPH * CH);
  int* start  = deg + N_NODES;
  int* cursor = start + N_NODES;
  int* csr    = cursor + N_NODES;
  int* gstart = csr + EDGES;
  int* gend   = gstart + NGRAPH;
  int* counter= gend + NGRAPH;

  const int* srcp = ei;
  const int* dstp = ei + EDGES;

  // ---- prep ----
  cvt_bf16_kernel<<<(N_NODES * FEAT / 4 + 255) / 256, 256, 0, stream>>>(x, xb, N_NODES * FEAT / 4);
  prep_weights<<<(L1_W + L2_W + 255) / 256, 256, 0, stream>>>(
      Wq1, Wk1, Wv1, Ws1, bq1, bk1, bv1, bs1,
      Wq2, Wk2, Wv2, bq2, bk2, bv2, Ws2, bs2, W1t, Bh1, W2t, Bh2);

  // ---- CSR build ----
  zero_kernel<<<(N_NODES + 255) / 256, 256, 0, stream>>>(deg, counter, gstart, gend, pooled);
  hist_bounds_kernel<<<(EDGES + 255) / 256, 256, 0, stream>>>(dstp, deg, batch, gstart, gend);
  alloc_kernel<<<(N_NODES + 255) / 256, 256, 0, stream>>>(deg, counter, start, cursor);
  scatter_kernel<<<(EDGES + 255) / 256, 256, 0, stream>>>(srcp, dstp, cursor, csr);

  const int gx = (N_NODES + 127) / 128;  // 391
  const int ga = (N_NODES + 3) / 4;      // 12500

  // ---- layer 1: per head-pair, GEMM (1024 cols) + attention (fused skip+ELU) ----
  for (int p = 0; p < 2; ++p) {
    gemm_bt<ushort_t><<<dim3(gx, 8), 256, 0, stream>>>(
        xb, W1t + (size_t)p * 1024 * FEAT, Bh1 + p * 1024, BIG, 1024, N_NODES, FEAT);
    attn1_kernel<<<dim3(ga, 2), 256, 0, stream>>>(BIG, start, deg, csr, H1b, p);
  }

  // ---- layer 2: pair0 GEMM includes skip cols (896, ldc=1024); attn2 writes S2 ----
  gemm_bt<ushort_t><<<dim3(gx, 7), 256, 0, stream>>>(
      H1b, W2t, Bh2, BIG, 1024, N_NODES, HID);
  attn2_kernel<<<ga, 256, 0, stream>>>(BIG, start, deg, csr, S2, 1);
  gemm_bt<ushort_t><<<dim3(gx, 6), 256, 0, stream>>>(
      H1b, W2t + (size_t)896 * HID, Bh2 + 896, BIG, 1024, N_NODES, HID);
  attn2_kernel<<<ga, 256, 0, stream>>>(BIG, start, deg, csr, S2, 0);

  // ---- pool (fused ELU) + classify ----
  pool_accum<<<(N_NODES * CH + 255) / 256, 256, 0, stream>>>(S2, batch, pooled);
  cls_kernel<<<NGRAPH, CH, 0, stream>>>(pooled, gstart, gend, Wfc, bfc, out);
}

// Round 6
// 760.321 us; speedup vs baseline: 4.2433x; 1.0053x over previous
//
#include <hip/hip_runtime.h>
#include <math.h>
#include <stdint.h>

#define N_NODES 50000
#define FEAT    256
#define EDGES   200000
#define HEADS   4
#define CH      128
#define HID     512   // HEADS*CH
#define NGRAPH  256
#define NCLS    10

typedef unsigned short ushort_t;
typedef unsigned int uint_t;
typedef __attribute__((ext_vector_type(8))) short bf16x8;
typedef __attribute__((ext_vector_type(4))) float f32x4;

__device__ __forceinline__ ushort_t f2bf(float f) {  // round-to-nearest-even
  uint_t u = __float_as_uint(f);
  u += 0x7FFF + ((u >> 16) & 1);
  return (ushort_t)(u >> 16);
}
__device__ __forceinline__ float bf2f(ushort_t h) {
  return __uint_as_float(((uint_t)h) << 16);
}
__device__ __forceinline__ void unpack8(uint4 w, float* f) {
  f[0] = bf2f((ushort_t)w.x); f[1] = bf2f((ushort_t)(w.x >> 16));
  f[2] = bf2f((ushort_t)w.y); f[3] = bf2f((ushort_t)(w.y >> 16));
  f[4] = bf2f((ushort_t)w.z); f[5] = bf2f((ushort_t)(w.z >> 16));
  f[6] = bf2f((ushort_t)w.w); f[7] = bf2f((ushort_t)(w.w >> 16));
}

// ---------------------------------------------------------------------------
// bf16 MFMA GEMM: C[M,N] = A[M,K] @ Bt[N,K]^T + bias (bf16 out)
// 128x128 tile, BK=64 (half the barrier drains of BK=32), 256 threads
// (4 waves 2x2), 4x4 16x16x32 MFMA tiles/wave, global_load_lds width-16
// staging, XOR-chunk swizzle (8 chunks/row). Epilogue repacks C through a
// per-wave LDS region for fully-coalesced dwordx4 stores.
// ---------------------------------------------------------------------------
__global__ __launch_bounds__(256) void gemm_bt(
    const ushort_t* __restrict__ A, const ushort_t* __restrict__ Bt,
    const float* __restrict__ bias, ushort_t* __restrict__ C, int ldc,
    int M, int K) {
  __shared__ __align__(16) ushort_t smem[2 * 128 * 64];  // 32 KB: sA | sB
  ushort_t* sA = smem;
  ushort_t* sB = smem + 128 * 64;
  const int tid = threadIdx.x;
  const int lane = tid & 63, wave = tid >> 6;
  const int wr = wave >> 1, wc = wave & 1;
  const int rowBase = blockIdx.x * 128, colBase = blockIdx.y * 128;
  f32x4 acc[4][4] = {};

  for (int k0 = 0; k0 < K; k0 += 64) {
    // stage 128 rows x 8 chunks(16B) per matrix; 4 insts x 256 threads
#pragma unroll
    for (int l = 0; l < 4; ++l) {
      int slot = l * 256 + tid;           // 0..1023
      int rl = slot >> 3;                 // row 0..127
      int pos = slot & 7;                 // stored chunk slot
      int cg = pos ^ (rl & 7);            // global chunk landing here
      {
        int row = rowBase + rl;
        row = row < M ? row : M - 1;      // clamp tail (epilogue guards)
        const ushort_t* gp = A + (size_t)row * K + k0 + cg * 8;
        __builtin_amdgcn_global_load_lds(
            (const __attribute__((address_space(1))) uint_t*)gp,
            (__attribute__((address_space(3))) uint_t*)(sA + slot * 8),
            16, 0, 0);
      }
      {
        int n = colBase + rl;             // N always multiple of 128
        const ushort_t* gp = Bt + (size_t)n * K + k0 + cg * 8;
        __builtin_amdgcn_global_load_lds(
            (const __attribute__((address_space(1))) uint_t*)gp,
            (__attribute__((address_space(3))) uint_t*)(sB + slot * 8),
            16, 0, 0);
      }
    }
    __syncthreads();
    const int fr = lane & 15, c0 = lane >> 4;
#pragma unroll
    for (int s = 0; s < 2; ++s) {
      int cc = s * 4 + c0;                // global chunk wanted
      bf16x8 af[4], bfr[4];
#pragma unroll
      for (int i = 0; i < 4; ++i) {
        int r = wr * 64 + i * 16 + fr;
        af[i] = *(const bf16x8*)(sA + r * 64 + (cc ^ (r & 7)) * 8);
        int n = wc * 64 + i * 16 + fr;
        bfr[i] = *(const bf16x8*)(sB + n * 64 + (cc ^ (n & 7)) * 8);
      }
#pragma unroll
      for (int i = 0; i < 4; ++i)
#pragma unroll
        for (int j = 0; j < 4; ++j)
          acc[i][j] = __builtin_amdgcn_mfma_f32_16x16x32_bf16(af[i], bfr[j], acc[i][j], 0, 0, 0);
    }
    __syncthreads();
  }

  // Epilogue: per-wave LDS repack (wave-private 8KB region; no barrier needed)
  // C/D layout col=lane&15, row=(lane>>4)*4+reg (m89-verified).
  ushort_t* wbuf = smem + wave * 4096;    // 64x64 bf16
  const int rq = lane >> 4, fc = lane & 15;
#pragma unroll
  for (int j = 0; j < 4; ++j) {
    float bv = bias[colBase + wc * 64 + j * 16 + fc];
#pragma unroll
    for (int i = 0; i < 4; ++i)
#pragma unroll
      for (int r = 0; r < 4; ++r) {
        int rl = i * 16 + rq * 4 + r;     // 0..63
        int cl = j * 16 + fc;             // 0..63
        int cs = cl ^ (((rl >> 2) & 7) * 8);  // bank-spread swizzle
        wbuf[rl * 64 + cs] = f2bf(acc[i][j][r] + bv);
      }
  }
  int rowg = rowBase + wr * 64 + lane;    // lane = local row
  if (rowg < M) {
    ushort_t* dst = C + (size_t)rowg * ldc + colBase + wc * 64;
    int v = (lane >> 2) & 7;
#pragma unroll
    for (int c = 0; c < 8; ++c) {
      uint4 val = *(const uint4*)(wbuf + lane * 64 + (c ^ v) * 8);
      *(uint4*)(dst + c * 8) = val;
    }
  }
}

// ---------------------------------------------------------------------------
// Prep: x -> bf16; weights -> transposed bf16 via 32x32 LDS tile transpose.
// W1t[2048][256]: n -> p=n>>10, hh=(n>>9)&1, sel=(n>>7)&3 (q,k,v,s),
//                 c=(2p+hh)*128+(n&127)
// W2t[1664][512]: n<768: heads 0,1 (q|k|v per 128); [768,896): skip (Ws2);
//                 n>=896: heads 2,3.
// ---------------------------------------------------------------------------
__global__ void cvt_bf16_kernel(const float* __restrict__ in, ushort_t* __restrict__ out, int n4) {
  int i = blockIdx.x * blockDim.x + threadIdx.x;
  if (i >= n4) return;
  float4 f = *(const float4*)(in + (size_t)i * 4);
  uint_t lo = (uint_t)f2bf(f.x) | ((uint_t)f2bf(f.y) << 16);
  uint_t hi = (uint_t)f2bf(f.z) | ((uint_t)f2bf(f.w) << 16);
  ((uint2*)out)[i] = make_uint2(lo, hi);
}

#define L1_W   (2048 * FEAT)
#define L2_W   (1664 * HID)
#define T1     512   // (2048/32)*(256/32)
#define T2     832   // (1664/32)*(512/32)

__global__ __launch_bounds__(256) void prep_tp(
    const float* __restrict__ Wq1, const float* __restrict__ Wk1,
    const float* __restrict__ Wv1, const float* __restrict__ Ws1,
    const float* __restrict__ Wq2, const float* __restrict__ Wk2,
    const float* __restrict__ Wv2, const float* __restrict__ Ws2,
    ushort_t* __restrict__ W1t, ushort_t* __restrict__ W2t) {
  __shared__ float tile[32][33];
  int t = blockIdx.x;
  const float* W; int ldw, c0, n0, k0, ldk; ushort_t* dst;
  if (t < T1) {
    int nb = t >> 3, kb = t & 7;
    n0 = nb * 32; k0 = kb * 32; ldk = FEAT; dst = W1t;
    int p = n0 >> 10, n1 = n0 & 1023, hh = n1 >> 9, sel = (n1 >> 7) & 3;
    c0 = (2 * p + hh) * CH + (n1 & (CH - 1));
    W = sel == 0 ? Wq1 : sel == 1 ? Wk1 : sel == 2 ? Wv1 : Ws1;
    ldw = HID;
  } else {
    t -= T1;
    int nb = t >> 4, kb = t & 15;
    n0 = nb * 32; k0 = kb * 32; ldk = HID; dst = W2t;
    if (n0 < 768 || n0 >= 896) {
      int n2 = (n0 < 768) ? n0 : n0 - 896;
      int hb = (n0 < 768) ? 0 : 2;
      int hh = hb + n2 / 384, r = n2 % 384, sel = r >> 7;
      c0 = hh * CH + (r & (CH - 1));
      W = sel == 0 ? Wq2 : sel == 1 ? Wk2 : Wv2;
      ldw = HID;
    } else {
      c0 = n0 - 768; W = Ws2; ldw = CH;
    }
  }
  int col = threadIdx.x & 31, rw = threadIdx.x >> 5;
#pragma unroll
  for (int ph = 0; ph < 4; ++ph) {
    int kk = rw + ph * 8;
    tile[kk][col] = W[(size_t)(k0 + kk) * ldw + c0 + col];   // coalesced read
  }
  __syncthreads();
#pragma unroll
  for (int ph = 0; ph < 4; ++ph) {
    int dn = rw + ph * 8;
    dst[(size_t)(n0 + dn) * ldk + k0 + col] = f2bf(tile[col][dn]);  // coalesced write
  }
}

__global__ void bias_kernel(
    const float* __restrict__ bq1, const float* __restrict__ bk1,
    const float* __restrict__ bv1, const float* __restrict__ bs1,
    const float* __restrict__ bq2, const float* __restrict__ bk2,
    const float* __restrict__ bv2, const float* __restrict__ bs2,
    float* __restrict__ Bh1, float* __restrict__ Bh2) {
  int n = blockIdx.x * blockDim.x + threadIdx.x;
  if (n < 2048) {
    int p = n >> 10, n1 = n & 1023, hh = n1 >> 9, sel = (n1 >> 7) & 3;
    int c = (2 * p + hh) * CH + (n1 & (CH - 1));
    const float* b = sel == 0 ? bq1 : sel == 1 ? bk1 : sel == 2 ? bv1 : bs1;
    Bh1[n] = b[c];
  } else {
    int n2 = n - 2048;
    if (n2 >= 1664) return;
    if (n2 < 768 || n2 >= 896) {
      int nn = (n2 < 768) ? n2 : n2 - 896;
      int hb = (n2 < 768) ? 0 : 2;
      int hh = hb + nn / 384, r = nn % 384, sel = r >> 7;
      int c = hh * CH + (r & (CH - 1));
      const float* b = sel == 0 ? bq2 : sel == 1 ? bk2 : bv2;
      Bh2[n2] = b[c];
    } else {
      Bh2[n2] = bs2[n2 - 768];
    }
  }
}

// ---------------------------------------------------------------------------
// CSR build: zero -> hist+bounds -> alloc (wave atomic) -> scatter
// ---------------------------------------------------------------------------
__global__ void zero_kernel(int* __restrict__ deg, int* __restrict__ counter,
                            int* __restrict__ gstart, int* __restrict__ gend,
                            float* __restrict__ pooled) {
  int i = blockIdx.x * blockDim.x + threadIdx.x;
  if (i < N_NODES) deg[i] = 0;
  if (i < NGRAPH) { gstart[i] = 0; gend[i] = 0; }
  if (i < NGRAPH * CH) pooled[i] = 0.f;
  if (i == 0) counter[0] = 0;
}

__global__ void hist_bounds_kernel(const int* __restrict__ dst, int* __restrict__ deg,
                                   const int* __restrict__ batch,
                                   int* __restrict__ gstart, int* __restrict__ gend) {
  int t = blockIdx.x * blockDim.x + threadIdx.x;
  if (t < EDGES) atomicAdd(&deg[dst[t]], 1);
  if (t < N_NODES) {
    int b = batch[t];
    if (t == 0 || batch[t - 1] != b) gstart[b] = t;
    if (t == N_NODES - 1 || batch[t + 1] != b) gend[b] = t + 1;
  }
}

__global__ void alloc_kernel(const int* __restrict__ deg, int* __restrict__ counter,
                             int* __restrict__ start, int* __restrict__ cursor) {
  int i = blockIdx.x * blockDim.x + threadIdx.x;
  int lane = threadIdx.x & 63;
  int v = (i < N_NODES) ? deg[i] : 0;
  int sum = v;
#pragma unroll
  for (int off = 1; off < 64; off <<= 1) {
    int t = __shfl_up(sum, off);
    if (lane >= off) sum += t;
  }
  int excl = sum - v;
  int waveTot = __shfl(sum, 63);
  int base = 0;
  if (lane == 63) base = atomicAdd(counter, waveTot);
  base = __shfl(base, 63);
  if (i < N_NODES) {
    start[i] = base + excl;
    cursor[i] = base + excl;
  }
}

__global__ void scatter_kernel(const int* __restrict__ src, const int* __restrict__ dst,
                               int* __restrict__ cursor, int* __restrict__ csr) {
  int e = blockIdx.x * blockDim.x + threadIdx.x;
  if (e < EDGES) {
    int pos = atomicAdd(&cursor[dst[e]], 1);
    csr[pos] = src[e];
  }
}

// ---------------------------------------------------------------------------
// Attention core: one wave per (node, head). 4 x 16-lane groups process 4
// edges in parallel (8 channels/lane, uint4 loads); per-group online-softmax
// states merged at the end via 2 butterfly rounds over lane bits 4,5.
// ---------------------------------------------------------------------------
__device__ __forceinline__ void attn_node_head(
    const ushort_t* __restrict__ buf, int stride, int off,
    int i, int li, int g, int beg, int end, const int* __restrict__ csr,
    float* a, float& sout) {
  float q[8];
  unpack8(*(const uint4*)(buf + (size_t)i * stride + off + li * 8), q);
  float m = -1e30f, s = 0.f;
#pragma unroll
  for (int c = 0; c < 8; ++c) a[c] = 0.f;
  for (int e0 = beg; e0 < end; e0 += 4) {
    int eg = e0 + g;
    bool valid = eg < end;
    int j = csr[valid ? eg : beg];
    const ushort_t* jp = buf + (size_t)j * stride + off;
    uint4 kw = *(const uint4*)(jp + CH + li * 8);
    uint4 vw = *(const uint4*)(jp + 2 * CH + li * 8);
    float kf[8]; unpack8(kw, kf);
    float p = q[0] * kf[0] + q[1] * kf[1] + q[2] * kf[2] + q[3] * kf[3] +
              q[4] * kf[4] + q[5] * kf[5] + q[6] * kf[6] + q[7] * kf[7];
    p += __shfl_xor(p, 1);
    p += __shfl_xor(p, 2);
    p += __shfl_xor(p, 4);
    p += __shfl_xor(p, 8);
    float alpha = valid ? p * 0.08838834764831845f : -1e30f;  // 1/sqrt(128)
    float mn = fmaxf(m, alpha);
    float sc = expf(m - mn);
    float w = valid ? expf(alpha - mn) : 0.f;
    float vf[8]; unpack8(vw, vf);
    s = s * sc + w;
#pragma unroll
    for (int c = 0; c < 8; ++c) a[c] = a[c] * sc + w * vf[c];
    m = mn;
  }
#pragma unroll
  for (int ox = 16; ox <= 32; ox <<= 1) {
    float mo = __shfl_xor(m, ox);
    float so = __shfl_xor(s, ox);
    float mn = fmaxf(m, mo);
    float sc1 = expf(m - mn), sc2 = expf(mo - mn);
    s = s * sc1 + so * sc2;
#pragma unroll
    for (int c = 0; c < 8; ++c) {
      float ao = __shfl_xor(a[c], ox);
      a[c] = a[c] * sc1 + ao * sc2;
    }
    m = mn;
  }
  sout = s;
}

// layer 1 (pair p, hh = blockIdx.y): stride 1024, q at hh*512, k/v/s at
// +128/+256/+384; fused skip-add + ELU; write H1b col (2p+hh)*128.
__global__ __launch_bounds__(256) void attn1_kernel(
    const ushort_t* __restrict__ QKVS2, const int* __restrict__ start,
    const int* __restrict__ deg, const int* __restrict__ csr,
    ushort_t* __restrict__ H1b, int p) {
  int wave = threadIdx.x >> 6, lane = threadIdx.x & 63;
  int li = lane & 15, g = lane >> 4;
  int i = blockIdx.x * 4 + wave;
  if (i >= N_NODES) return;
  int hh = blockIdx.y;
  int beg = start[i], end = beg + deg[i];
  float a[8], s;
  attn_node_head(QKVS2, 1024, hh * 512, i, li, g, beg, end, csr, a, s);
  if (g != 0) return;
  float inv = 1.f / (s + 1e-16f);
  float sk[8];
  unpack8(*(const uint4*)(QKVS2 + (size_t)i * 1024 + hh * 512 + 384 + li * 8), sk);
  uint4 ow;
  uint_t* op = (uint_t*)&ow;
#pragma unroll
  for (int c = 0; c < 4; ++c) {
    float o0 = a[2 * c] * inv + sk[2 * c];
    float o1 = a[2 * c + 1] * inv + sk[2 * c + 1];
    o0 = o0 > 0.f ? o0 : expm1f(o0);
    o1 = o1 > 0.f ? o1 : expm1f(o1);
    op[c] = (uint_t)f2bf(o0) | ((uint_t)f2bf(o1) << 16);
  }
  *(uint4*)(H1b + (size_t)i * HID + (2 * p + hh) * CH + li * 8) = ow;
}

// layer 2: one wave per node, loops 2 heads (offsets 0, 384; stride 1024).
// first=1: S2 = skip(bf16 at col 768) + 0.25*(m0+m1); else S2 += ...
__global__ __launch_bounds__(256) void attn2_kernel(
    const ushort_t* __restrict__ buf, const int* __restrict__ start,
    const int* __restrict__ deg, const int* __restrict__ csr,
    float* __restrict__ S2, int first) {
  int wave = threadIdx.x >> 6, lane = threadIdx.x & 63;
  int li = lane & 15, g = lane >> 4;
  int i = blockIdx.x * 4 + wave;
  if (i >= N_NODES) return;
  int beg = start[i], end = beg + deg[i];
  float msum[8] = {};
  for (int hh = 0; hh < 2; ++hh) {
    float a[8], s;
    attn_node_head(buf, 1024, hh * 384, i, li, g, beg, end, csr, a, s);
    float inv = 0.25f / (s + 1e-16f);
#pragma unroll
    for (int c = 0; c < 8; ++c) msum[c] += a[c] * inv;
  }
  if (g != 0) return;
  float* sp = S2 + (size_t)i * CH + li * 8;
  if (first) {
    float sk[8];
    unpack8(*(const uint4*)(buf + (size_t)i * 1024 + 768 + li * 8), sk);
#pragma unroll
    for (int c = 0; c < 8; ++c) sp[c] = sk[c] + msum[c];
  } else {
#pragma unroll
    for (int c = 0; c < 8; ++c) sp[c] += msum[c];
  }
}

// ---------------------------------------------------------------------------
// Pool: node-parallel ELU + atomic accumulate into pooled[G][CH].
// ---------------------------------------------------------------------------
__global__ void pool_accum(const float* __restrict__ S2, const int* __restrict__ batch,
                           float* __restrict__ pooled) {
  int idx = blockIdx.x * blockDim.x + threadIdx.x;
  if (idx >= N_NODES * CH) return;
  int i = idx >> 7, c = idx & (CH - 1);
  float v = S2[idx];
  v = v > 0.f ? v : expm1f(v);
  atomicAdd(&pooled[batch[i] * CH + c], v);
}

__global__ __launch_bounds__(128) void cls_kernel(
    const float* __restrict__ pooled, const int* __restrict__ gstart,
    const int* __restrict__ gend, const float* __restrict__ Wfc,
    const float* __restrict__ bfc, float* __restrict__ out) {
  int g = blockIdx.x;
  int t = threadIdx.x;
  float cnt = fmaxf((float)(gend[g] - gstart[g]), 1.f);
  __shared__ float red[CH];
  __shared__ float logits[NCLS];
  float pv = pooled[g * CH + t] / cnt;
  for (int c = 0; c < NCLS; ++c) {
    __syncthreads();
    red[t] = pv * Wfc[t * NCLS + c];
    __syncthreads();
    for (int off = 64; off > 0; off >>= 1) {
      if (t < off) red[t] += red[t + off];
      __syncthreads();
    }
    if (t == 0) logits[c] = red[0] + bfc[c];
  }
  __syncthreads();
  if (t == 0) {
    float mx = -INFINITY;
    for (int c = 0; c < NCLS; ++c) mx = fmaxf(mx, logits[c]);
    float se = 0.f;
    for (int c = 0; c < NCLS; ++c) se += expf(logits[c] - mx);
    float ls = mx + logf(se);
    for (int c = 0; c < NCLS; ++c) out[g * NCLS + c] = logits[c] - ls;
  }
}

// ---------------------------------------------------------------------------
extern "C" void kernel_launch(void* const* d_in, const int* in_sizes, int n_in,
                              void* d_out, int out_size, void* d_ws, size_t ws_size,
                              hipStream_t stream) {
  const float* x    = (const float*)d_in[0];
  const int*   ei   = (const int*)d_in[1];
  const int*   batch= (const int*)d_in[2];
  const float* Wq1 = (const float*)d_in[3];  const float* bq1 = (const float*)d_in[4];
  const float* Wk1 = (const float*)d_in[5];  const float* bk1 = (const float*)d_in[6];
  const float* Wv1 = (const float*)d_in[7];  const float* bv1 = (const float*)d_in[8];
  const float* Ws1 = (const float*)d_in[9];  const float* bs1 = (const float*)d_in[10];
  const float* Wq2 = (const float*)d_in[11]; const float* bq2 = (const float*)d_in[12];
  const float* Wk2 = (const float*)d_in[13]; const float* bk2 = (const float*)d_in[14];
  const float* Wv2 = (const float*)d_in[15]; const float* bv2 = (const float*)d_in[16];
  const float* Ws2 = (const float*)d_in[17]; const float* bs2 = (const float*)d_in[18];
  const float* Wfc = (const float*)d_in[19]; const float* bfc = (const float*)d_in[20];
  float* out = (float*)d_out;

  // Workspace (~183 MB). S2 (fp32 N*128 = 25.6MB) aliases xb (dead after L1 GEMMs).
  ushort_t* xb   = (ushort_t*)d_ws;                    // N x 256 bf16
  float*    S2   = (float*)d_ws;                       // N x 128 fp32 (aliases xb)
  ushort_t* BIG  = xb + (size_t)N_NODES * FEAT;        // N x 1024 bf16
  ushort_t* H1b  = BIG + (size_t)N_NODES * 1024;       // N x 512 bf16
  ushort_t* W1t  = H1b + (size_t)N_NODES * HID;        // 2048*256
  float*    Bh1  = (float*)(W1t + L1_W);               // 2048
  ushort_t* W2t  = (ushort_t*)(Bh1 + 2048);            // 1664*512
  float*    Bh2  = (float*)(W2t + L2_W);               // 1664
  float*    pooled = Bh2 + 1664;                       // 256*128
  int* deg    = (int*)(pooled + NGRAPH * CH);
  int* start  = deg + N_NODES;
  int* cursor = start + N_NODES;
  int* csr    = cursor + N_NODES;
  int* gstart = csr + EDGES;
  int* gend   = gstart + NGRAPH;
  int* counter= gend + NGRAPH;

  const int* srcp = ei;
  const int* dstp = ei + EDGES;

  // ---- prep ----
  cvt_bf16_kernel<<<(N_NODES * FEAT / 4 + 255) / 256, 256, 0, stream>>>(x, xb, N_NODES * FEAT / 4);
  prep_tp<<<T1 + T2, 256, 0, stream>>>(Wq1, Wk1, Wv1, Ws1, Wq2, Wk2, Wv2, Ws2, W1t, W2t);
  bias_kernel<<<(2048 + 1664 + 255) / 256, 256, 0, stream>>>(
      bq1, bk1, bv1, bs1, bq2, bk2, bv2, bs2, Bh1, Bh2);

  // ---- CSR build ----
  zero_kernel<<<(N_NODES + 255) / 256, 256, 0, stream>>>(deg, counter, gstart, gend, pooled);
  hist_bounds_kernel<<<(EDGES + 255) / 256, 256, 0, stream>>>(dstp, deg, batch, gstart, gend);
  alloc_kernel<<<(N_NODES + 255) / 256, 256, 0, stream>>>(deg, counter, start, cursor);
  scatter_kernel<<<(EDGES + 255) / 256, 256, 0, stream>>>(srcp, dstp, cursor, csr);

  const int gx = (N_NODES + 127) / 128;  // 391
  const int ga = (N_NODES + 3) / 4;      // 12500

  // ---- layer 1: per head-pair, GEMM (1024 cols) + attention (fused skip+ELU) ----
  for (int p = 0; p < 2; ++p) {
    gemm_bt<<<dim3(gx, 8), 256, 0, stream>>>(
        xb, W1t + (size_t)p * 1024 * FEAT, Bh1 + p * 1024, BIG, 1024, N_NODES, FEAT);
    attn1_kernel<<<dim3(ga, 2), 256, 0, stream>>>(BIG, start, deg, csr, H1b, p);
  }

  // ---- layer 2: pair0 GEMM includes skip cols (896, ldc=1024); attn2 writes S2 ----
  gemm_bt<<<dim3(gx, 7), 256, 0, stream>>>(
      H1b, W2t, Bh2, BIG, 1024, N_NODES, HID);
  attn2_kernel<<<ga, 256, 0, stream>>>(BIG, start, deg, csr, S2, 1);
  gemm_bt<<<dim3(gx, 6), 256, 0, stream>>>(
      H1b, W2t + (size_t)896 * HID, Bh2 + 896, BIG, 1024, N_NODES, HID);
  attn2_kernel<<<ga, 256, 0, stream>>>(BIG, start, deg, csr, S2, 0);

  // ---- pool (fused ELU) + classify ----
  pool_accum<<<(N_NODES * CH + 255) / 256, 256, 0, stream>>>(S2, batch, pooled);
  cls_kernel<<<NGRAPH, CH, 0, stream>>>(pooled, gstart, gend, Wfc, bfc, out);
}

// Round 7
// 677.595 us; speedup vs baseline: 4.7613x; 1.1221x over previous
//
#include <hip/hip_runtime.h>
#include <math.h>
#include <stdint.h>

#define N_NODES 50000
#define FEAT    256
#define EDGES   200000
#define HEADS   4
#define CH      128
#define HID     512   // HEADS*CH
#define NGRAPH  256
#define NCLS    10

typedef unsigned short ushort_t;
typedef unsigned int uint_t;
typedef __attribute__((ext_vector_type(8))) short bf16x8;
typedef __attribute__((ext_vector_type(4))) float f32x4;

__device__ __forceinline__ ushort_t f2bf(float f) {  // round-to-nearest-even
  uint_t u = __float_as_uint(f);
  u += 0x7FFF + ((u >> 16) & 1);
  return (ushort_t)(u >> 16);
}
__device__ __forceinline__ float bf2f(ushort_t h) {
  return __uint_as_float(((uint_t)h) << 16);
}
__device__ __forceinline__ void unpack8(uint4 w, float* f) {
  f[0] = bf2f((ushort_t)w.x); f[1] = bf2f((ushort_t)(w.x >> 16));
  f[2] = bf2f((ushort_t)w.y); f[3] = bf2f((ushort_t)(w.y >> 16));
  f[4] = bf2f((ushort_t)w.z); f[5] = bf2f((ushort_t)(w.z >> 16));
  f[6] = bf2f((ushort_t)w.w); f[7] = bf2f((ushort_t)(w.w >> 16));
}

// ---------------------------------------------------------------------------
// bf16 MFMA GEMM: C[M,N] = A[M,K] @ Bt[N,K]^T + bias (bf16 out)
// 128x128 tile, BK=32 (16 KB LDS -> high occupancy; round-6 showed BK=64's
// 32 KB LDS regressed), 256 threads (4 waves 2x2), 4x4 16x16x32 MFMA/wave.
// 1-D grid, XCD-swizzled: the ncol column-tiles of one row-tile share b%8
// (same XCD) within a 64-block window -> A-tile fetched ~once per XCD-L2.
// Epilogue repacks per-wave 32-row halves through LDS (4 KB/wave, fits the
// same 16 KB) and stores 8 rows x 8 chunks per dwordx4 instruction.
// ---------------------------------------------------------------------------
__global__ __launch_bounds__(256) void gemm_bt(
    const ushort_t* __restrict__ A, const ushort_t* __restrict__ Bt,
    const float* __restrict__ bias, ushort_t* __restrict__ C, int ldc,
    int M, int K, int ncol) {
  __shared__ __align__(16) ushort_t smem[8192];   // 16 KB total
  ushort_t* sA = smem;                            // 128 x 32
  ushort_t* sB = smem + 4096;                     // 128 x 32
  const int tid = threadIdx.x;
  const int lane = tid & 63, wave = tid >> 6;
  const int wr = wave >> 1, wc = wave & 1;

  // XCD-aware decode: rt = grp*8 + (b%8), c = (b/8)%ncol
  int b = blockIdx.x;
  int per = ncol << 3;
  int grp = b / per;
  int rem = b - grp * per;
  int rloc = rem & 7;
  int c = rem >> 3;
  const int rowBase = (grp * 8 + rloc) * 128;
  const int colBase = c * 128;
  if (rowBase >= M) return;

  f32x4 acc[4][4] = {};

  for (int k0 = 0; k0 < K; k0 += 32) {
#pragma unroll
    for (int l = 0; l < 2; ++l) {
      int slot = l * 256 + tid;           // 0..511
      int rl = slot >> 2;                 // row/col 0..127
      int pos = slot & 3;                 // stored chunk slot
      int cg = pos ^ (rl & 3);            // swizzled global chunk
      {
        int row = rowBase + rl;
        row = row < M ? row : M - 1;      // clamp tail (epilogue guards)
        const ushort_t* gp = A + (size_t)row * K + k0 + cg * 8;
        __builtin_amdgcn_global_load_lds(
            (const __attribute__((address_space(1))) uint_t*)gp,
            (__attribute__((address_space(3))) uint_t*)(sA + slot * 8),
            16, 0, 0);
      }
      {
        int n = colBase + rl;
        const ushort_t* gp = Bt + (size_t)n * K + k0 + cg * 8;
        __builtin_amdgcn_global_load_lds(
            (const __attribute__((address_space(1))) uint_t*)gp,
            (__attribute__((address_space(3))) uint_t*)(sB + slot * 8),
            16, 0, 0);
      }
    }
    __syncthreads();
    const int fr = lane & 15, c0 = lane >> 4;
    bf16x8 af[4], bfr[4];
#pragma unroll
    for (int i = 0; i < 4; ++i) {
      int r = wr * 64 + i * 16 + fr;
      af[i] = *(const bf16x8*)(sA + r * 32 + ((c0 ^ (r & 3)) * 8));
      int n = wc * 64 + i * 16 + fr;
      bfr[i] = *(const bf16x8*)(sB + n * 32 + ((c0 ^ (n & 3)) * 8));
    }
#pragma unroll
    for (int i = 0; i < 4; ++i)
#pragma unroll
      for (int j = 0; j < 4; ++j)
        acc[i][j] = __builtin_amdgcn_mfma_f32_16x16x32_bf16(af[i], bfr[j], acc[i][j], 0, 0, 0);
    __syncthreads();
  }

  // Epilogue: per-wave LDS repack in two 32-row halves (4 KB/wave region).
  // C/D layout col=lane&15, row=(lane>>4)*4+reg (m89-verified). Same-wave DS
  // ops execute in order; no barrier needed inside the halves loop.
  ushort_t* wbuf = smem + wave * 2048;    // 32 x 64 bf16
  const int rq = lane >> 4, fc = lane & 15;
  float bv[4];
#pragma unroll
  for (int j = 0; j < 4; ++j) bv[j] = bias[colBase + wc * 64 + j * 16 + fc];
#pragma unroll
  for (int h = 0; h < 2; ++h) {
#pragma unroll
    for (int ii = 0; ii < 2; ++ii) {
      int i = h * 2 + ii;
#pragma unroll
      for (int j = 0; j < 4; ++j)
#pragma unroll
        for (int r = 0; r < 4; ++r) {
          int rl = ii * 16 + rq * 4 + r;          // 0..31
          int cl = j * 16 + fc;                   // 0..63
          int cs = cl ^ (((rl >> 2) & 7) << 3);   // bank-spread swizzle
          wbuf[rl * 64 + cs] = f2bf(acc[i][j][r] + bv[j]);
        }
    }
    // read back: 8 chunks/row, 8 rows per instruction (contiguous 128B segs)
    int ci = lane & 7;
    int rbase = lane >> 3;                         // 0..7
#pragma unroll
    for (int rg = 0; rg < 4; ++rg) {
      int rr = rg * 8 + rbase;                     // 0..31
      int rowg = rowBase + wr * 64 + h * 32 + rr;
      int q = (rr >> 2) & 7;
      uint4 val = *(const uint4*)(wbuf + rr * 64 + ((ci ^ q) << 3));
      if (rowg < M)
        *(uint4*)(C + (size_t)rowg * ldc + colBase + wc * 64 + ci * 8) = val;
    }
  }
}

// ---------------------------------------------------------------------------
// Prep: x -> bf16; weights -> transposed bf16 via 32x32 LDS tile transpose.
// W1t[2048][256]: n -> p=n>>10, hh=(n>>9)&1, sel=(n>>7)&3 (q,k,v,s),
//                 c=(2p+hh)*128+(n&127)
// W2t[1664][512]: n<768: heads 0,1 (q|k|v per 128); [768,896): skip (Ws2);
//                 n>=896: heads 2,3.
// ---------------------------------------------------------------------------
__global__ void cvt_bf16_kernel(const float* __restrict__ in, ushort_t* __restrict__ out, int n4) {
  int i = blockIdx.x * blockDim.x + threadIdx.x;
  if (i >= n4) return;
  float4 f = *(const float4*)(in + (size_t)i * 4);
  uint_t lo = (uint_t)f2bf(f.x) | ((uint_t)f2bf(f.y) << 16);
  uint_t hi = (uint_t)f2bf(f.z) | ((uint_t)f2bf(f.w) << 16);
  ((uint2*)out)[i] = make_uint2(lo, hi);
}

#define L1_W   (2048 * FEAT)
#define L2_W   (1664 * HID)
#define T1     512   // (2048/32)*(256/32)
#define T2     832   // (1664/32)*(512/32)

__global__ __launch_bounds__(256) void prep_tp(
    const float* __restrict__ Wq1, const float* __restrict__ Wk1,
    const float* __restrict__ Wv1, const float* __restrict__ Ws1,
    const float* __restrict__ Wq2, const float* __restrict__ Wk2,
    const float* __restrict__ Wv2, const float* __restrict__ Ws2,
    ushort_t* __restrict__ W1t, ushort_t* __restrict__ W2t) {
  __shared__ float tile[32][33];
  int t = blockIdx.x;
  const float* W; int ldw, c0, n0, k0, ldk; ushort_t* dst;
  if (t < T1) {
    int nb = t >> 3, kb = t & 7;
    n0 = nb * 32; k0 = kb * 32; ldk = FEAT; dst = W1t;
    int p = n0 >> 10, n1 = n0 & 1023, hh = n1 >> 9, sel = (n1 >> 7) & 3;
    c0 = (2 * p + hh) * CH + (n1 & (CH - 1));
    W = sel == 0 ? Wq1 : sel == 1 ? Wk1 : sel == 2 ? Wv1 : Ws1;
    ldw = HID;
  } else {
    t -= T1;
    int nb = t >> 4, kb = t & 15;
    n0 = nb * 32; k0 = kb * 32; ldk = HID; dst = W2t;
    if (n0 < 768 || n0 >= 896) {
      int n2 = (n0 < 768) ? n0 : n0 - 896;
      int hb = (n0 < 768) ? 0 : 2;
      int hh = hb + n2 / 384, r = n2 % 384, sel = r >> 7;
      c0 = hh * CH + (r & (CH - 1));
      W = sel == 0 ? Wq2 : sel == 1 ? Wk2 : Wv2;
      ldw = HID;
    } else {
      c0 = n0 - 768; W = Ws2; ldw = CH;
    }
  }
  int col = threadIdx.x & 31, rw = threadIdx.x >> 5;
#pragma unroll
  for (int ph = 0; ph < 4; ++ph) {
    int kk = rw + ph * 8;
    tile[kk][col] = W[(size_t)(k0 + kk) * ldw + c0 + col];   // coalesced read
  }
  __syncthreads();
#pragma unroll
  for (int ph = 0; ph < 4; ++ph) {
    int dn = rw + ph * 8;
    dst[(size_t)(n0 + dn) * ldk + k0 + col] = f2bf(tile[col][dn]);  // coalesced write
  }
}

__global__ void bias_kernel(
    const float* __restrict__ bq1, const float* __restrict__ bk1,
    const float* __restrict__ bv1, const float* __restrict__ bs1,
    const float* __restrict__ bq2, const float* __restrict__ bk2,
    const float* __restrict__ bv2, const float* __restrict__ bs2,
    float* __restrict__ Bh1, float* __restrict__ Bh2) {
  int n = blockIdx.x * blockDim.x + threadIdx.x;
  if (n < 2048) {
    int p = n >> 10, n1 = n & 1023, hh = n1 >> 9, sel = (n1 >> 7) & 3;
    int c = (2 * p + hh) * CH + (n1 & (CH - 1));
    const float* b = sel == 0 ? bq1 : sel == 1 ? bk1 : sel == 2 ? bv1 : bs1;
    Bh1[n] = b[c];
  } else {
    int n2 = n - 2048;
    if (n2 >= 1664) return;
    if (n2 < 768 || n2 >= 896) {
      int nn = (n2 < 768) ? n2 : n2 - 896;
      int hb = (n2 < 768) ? 0 : 2;
      int hh = hb + nn / 384, r = nn % 384, sel = r >> 7;
      int c = hh * CH + (r & (CH - 1));
      const float* b = sel == 0 ? bq2 : sel == 1 ? bk2 : bv2;
      Bh2[n2] = b[c];
    } else {
      Bh2[n2] = bs2[n2 - 768];
    }
  }
}

// ---------------------------------------------------------------------------
// CSR build: zero -> hist+bounds -> alloc (wave atomic) -> scatter
// ---------------------------------------------------------------------------
__global__ void zero_kernel(int* __restrict__ deg, int* __restrict__ counter,
                            int* __restrict__ gstart, int* __restrict__ gend,
                            float* __restrict__ pooled) {
  int i = blockIdx.x * blockDim.x + threadIdx.x;
  if (i < N_NODES) deg[i] = 0;
  if (i < NGRAPH) { gstart[i] = 0; gend[i] = 0; }
  if (i < NGRAPH * CH) pooled[i] = 0.f;
  if (i == 0) counter[0] = 0;
}

__global__ void hist_bounds_kernel(const int* __restrict__ dst, int* __restrict__ deg,
                                   const int* __restrict__ batch,
                                   int* __restrict__ gstart, int* __restrict__ gend) {
  int t = blockIdx.x * blockDim.x + threadIdx.x;
  if (t < EDGES) atomicAdd(&deg[dst[t]], 1);
  if (t < N_NODES) {
    int b = batch[t];
    if (t == 0 || batch[t - 1] != b) gstart[b] = t;
    if (t == N_NODES - 1 || batch[t + 1] != b) gend[b] = t + 1;
  }
}

__global__ void alloc_kernel(const int* __restrict__ deg, int* __restrict__ counter,
                             int* __restrict__ start, int* __restrict__ cursor) {
  int i = blockIdx.x * blockDim.x + threadIdx.x;
  int lane = threadIdx.x & 63;
  int v = (i < N_NODES) ? deg[i] : 0;
  int sum = v;
#pragma unroll
  for (int off = 1; off < 64; off <<= 1) {
    int t = __shfl_up(sum, off);
    if (lane >= off) sum += t;
  }
  int excl = sum - v;
  int waveTot = __shfl(sum, 63);
  int base = 0;
  if (lane == 63) base = atomicAdd(counter, waveTot);
  base = __shfl(base, 63);
  if (i < N_NODES) {
    start[i] = base + excl;
    cursor[i] = base + excl;
  }
}

__global__ void scatter_kernel(const int* __restrict__ src, const int* __restrict__ dst,
                               int* __restrict__ cursor, int* __restrict__ csr) {
  int e = blockIdx.x * blockDim.x + threadIdx.x;
  if (e < EDGES) {
    int pos = atomicAdd(&cursor[dst[e]], 1);
    csr[pos] = src[e];
  }
}

// ---------------------------------------------------------------------------
// Attention core: one wave per (node, head). 4 x 16-lane groups process 4
// edges in parallel (8 channels/lane, uint4 loads); per-group online-softmax
// states merged at the end via 2 butterfly rounds over lane bits 4,5.
// ---------------------------------------------------------------------------
__device__ __forceinline__ void attn_node_head(
    const ushort_t* __restrict__ buf, int stride, int off,
    int i, int li, int g, int beg, int end, const int* __restrict__ csr,
    float* a, float& sout) {
  float q[8];
  unpack8(*(const uint4*)(buf + (size_t)i * stride + off + li * 8), q);
  float m = -1e30f, s = 0.f;
#pragma unroll
  for (int c = 0; c < 8; ++c) a[c] = 0.f;
  for (int e0 = beg; e0 < end; e0 += 4) {
    int eg = e0 + g;
    bool valid = eg < end;
    int j = csr[valid ? eg : beg];
    const ushort_t* jp = buf + (size_t)j * stride + off;
    uint4 kw = *(const uint4*)(jp + CH + li * 8);
    uint4 vw = *(const uint4*)(jp + 2 * CH + li * 8);
    float kf[8]; unpack8(kw, kf);
    float p = q[0] * kf[0] + q[1] * kf[1] + q[2] * kf[2] + q[3] * kf[3] +
              q[4] * kf[4] + q[5] * kf[5] + q[6] * kf[6] + q[7] * kf[7];
    p += __shfl_xor(p, 1);
    p += __shfl_xor(p, 2);
    p += __shfl_xor(p, 4);
    p += __shfl_xor(p, 8);
    float alpha = valid ? p * 0.08838834764831845f : -1e30f;  // 1/sqrt(128)
    float mn = fmaxf(m, alpha);
    float sc = expf(m - mn);
    float w = valid ? expf(alpha - mn) : 0.f;
    float vf[8]; unpack8(vw, vf);
    s = s * sc + w;
#pragma unroll
    for (int c = 0; c < 8; ++c) a[c] = a[c] * sc + w * vf[c];
    m = mn;
  }
#pragma unroll
  for (int ox = 16; ox <= 32; ox <<= 1) {
    float mo = __shfl_xor(m, ox);
    float so = __shfl_xor(s, ox);
    float mn = fmaxf(m, mo);
    float sc1 = expf(m - mn), sc2 = expf(mo - mn);
    s = s * sc1 + so * sc2;
#pragma unroll
    for (int c = 0; c < 8; ++c) {
      float ao = __shfl_xor(a[c], ox);
      a[c] = a[c] * sc1 + ao * sc2;
    }
    m = mn;
  }
  sout = s;
}

// layer 1 (pair p, hh = blockIdx.y): stride 1024, q at hh*512, k/v/s at
// +128/+256/+384; fused skip-add + ELU; write H1b col (2p+hh)*128.
__global__ __launch_bounds__(256) void attn1_kernel(
    const ushort_t* __restrict__ QKVS2, const int* __restrict__ start,
    const int* __restrict__ deg, const int* __restrict__ csr,
    ushort_t* __restrict__ H1b, int p) {
  int wave = threadIdx.x >> 6, lane = threadIdx.x & 63;
  int li = lane & 15, g = lane >> 4;
  int i = blockIdx.x * 4 + wave;
  if (i >= N_NODES) return;
  int hh = blockIdx.y;
  int beg = start[i], end = beg + deg[i];
  float a[8], s;
  attn_node_head(QKVS2, 1024, hh * 512, i, li, g, beg, end, csr, a, s);
  if (g != 0) return;
  float inv = 1.f / (s + 1e-16f);
  float sk[8];
  unpack8(*(const uint4*)(QKVS2 + (size_t)i * 1024 + hh * 512 + 384 + li * 8), sk);
  uint4 ow;
  uint_t* op = (uint_t*)&ow;
#pragma unroll
  for (int c = 0; c < 4; ++c) {
    float o0 = a[2 * c] * inv + sk[2 * c];
    float o1 = a[2 * c + 1] * inv + sk[2 * c + 1];
    o0 = o0 > 0.f ? o0 : expm1f(o0);
    o1 = o1 > 0.f ? o1 : expm1f(o1);
    op[c] = (uint_t)f2bf(o0) | ((uint_t)f2bf(o1) << 16);
  }
  *(uint4*)(H1b + (size_t)i * HID + (2 * p + hh) * CH + li * 8) = ow;
}

// layer 2: one wave per node, loops 2 heads (offsets 0, 384; stride 1024).
// first=1: S2 = skip(bf16 at col 768) + 0.25*(m0+m1); else S2 += ...
__global__ __launch_bounds__(256) void attn2_kernel(
    const ushort_t* __restrict__ buf, const int* __restrict__ start,
    const int* __restrict__ deg, const int* __restrict__ csr,
    float* __restrict__ S2, int first) {
  int wave = threadIdx.x >> 6, lane = threadIdx.x & 63;
  int li = lane & 15, g = lane >> 4;
  int i = blockIdx.x * 4 + wave;
  if (i >= N_NODES) return;
  int beg = start[i], end = beg + deg[i];
  float msum[8] = {};
  for (int hh = 0; hh < 2; ++hh) {
    float a[8], s;
    attn_node_head(buf, 1024, hh * 384, i, li, g, beg, end, csr, a, s);
    float inv = 0.25f / (s + 1e-16f);
#pragma unroll
    for (int c = 0; c < 8; ++c) msum[c] += a[c] * inv;
  }
  if (g != 0) return;
  float* sp = S2 + (size_t)i * CH + li * 8;
  if (first) {
    float sk[8];
    unpack8(*(const uint4*)(buf + (size_t)i * 1024 + 768 + li * 8), sk);
#pragma unroll
    for (int c = 0; c < 8; ++c) sp[c] = sk[c] + msum[c];
  } else {
#pragma unroll
    for (int c = 0; c < 8; ++c) sp[c] += msum[c];
  }
}

// ---------------------------------------------------------------------------
// Pool: node-parallel ELU + atomic accumulate into pooled[G][CH].
// ---------------------------------------------------------------------------
__global__ void pool_accum(const float* __restrict__ S2, const int* __restrict__ batch,
                           float* __restrict__ pooled) {
  int idx = blockIdx.x * blockDim.x + threadIdx.x;
  if (idx >= N_NODES * CH) return;
  int i = idx >> 7, c = idx & (CH - 1);
  float v = S2[idx];
  v = v > 0.f ? v : expm1f(v);
  atomicAdd(&pooled[batch[i] * CH + c], v);
}

__global__ __launch_bounds__(128) void cls_kernel(
    const float* __restrict__ pooled, const int* __restrict__ gstart,
    const int* __restrict__ gend, const float* __restrict__ Wfc,
    const float* __restrict__ bfc, float* __restrict__ out) {
  int g = blockIdx.x;
  int t = threadIdx.x;
  float cnt = fmaxf((float)(gend[g] - gstart[g]), 1.f);
  __shared__ float red[CH];
  __shared__ float logits[NCLS];
  float pv = pooled[g * CH + t] / cnt;
  for (int c = 0; c < NCLS; ++c) {
    __syncthreads();
    red[t] = pv * Wfc[t * NCLS + c];
    __syncthreads();
    for (int off = 64; off > 0; off >>= 1) {
      if (t < off) red[t] += red[t + off];
      __syncthreads();
    }
    if (t == 0) logits[c] = red[0] + bfc[c];
  }
  __syncthreads();
  if (t == 0) {
    float mx = -INFINITY;
    for (int c = 0; c < NCLS; ++c) mx = fmaxf(mx, logits[c]);
    float se = 0.f;
    for (int c = 0; c < NCLS; ++c) se += expf(logits[c] - mx);
    float ls = mx + logf(se);
    for (int c = 0; c < NCLS; ++c) out[g * NCLS + c] = logits[c] - ls;
  }
}

// ---------------------------------------------------------------------------
extern "C" void kernel_launch(void* const* d_in, const int* in_sizes, int n_in,
                              void* d_out, int out_size, void* d_ws, size_t ws_size,
                              hipStream_t stream) {
  const float* x    = (const float*)d_in[0];
  const int*   ei   = (const int*)d_in[1];
  const int*   batch= (const int*)d_in[2];
  const float* Wq1 = (const float*)d_in[3];  const float* bq1 = (const float*)d_in[4];
  const float* Wk1 = (const float*)d_in[5];  const float* bk1 = (const float*)d_in[6];
  const float* Wv1 = (const float*)d_in[7];  const float* bv1 = (const float*)d_in[8];
  const float* Ws1 = (const float*)d_in[9];  const float* bs1 = (const float*)d_in[10];
  const float* Wq2 = (const float*)d_in[11]; const float* bq2 = (const float*)d_in[12];
  const float* Wk2 = (const float*)d_in[13]; const float* bk2 = (const float*)d_in[14];
  const float* Wv2 = (const float*)d_in[15]; const float* bv2 = (const float*)d_in[16];
  const float* Ws2 = (const float*)d_in[17]; const float* bs2 = (const float*)d_in[18];
  const float* Wfc = (const float*)d_in[19]; const float* bfc = (const float*)d_in[20];
  float* out = (float*)d_out;

  // Workspace (~183 MB). S2 (fp32 N*128 = 25.6MB) aliases xb (dead after L1 GEMMs).
  ushort_t* xb   = (ushort_t*)d_ws;                    // N x 256 bf16
  float*    S2   = (float*)d_ws;                       // N x 128 fp32 (aliases xb)
  ushort_t* BIG  = xb + (size_t)N_NODES * FEAT;        // N x 1024 bf16
  ushort_t* H1b  = BIG + (size_t)N_NODES * 1024;       // N x 512 bf16
  ushort_t* W1t  = H1b + (size_t)N_NODES * HID;        // 2048*256
  float*    Bh1  = (float*)(W1t + L1_W);               // 2048
  ushort_t* W2t  = (ushort_t*)(Bh1 + 2048);            // 1664*512
  float*    Bh2  = (float*)(W2t + L2_W);               // 1664
  float*    pooled = Bh2 + 1664;                       // 256*128
  int* deg    = (int*)(pooled + NGRAPH * CH);
  int* start  = deg + N_NODES;
  int* cursor = start + N_NODES;
  int* csr    = cursor + N_NODES;
  int* gstart = csr + EDGES;
  int* gend   = gstart + NGRAPH;
  int* counter= gend + NGRAPH;

  const int* srcp = ei;
  const int* dstp = ei + EDGES;

  // ---- prep ----
  cvt_bf16_kernel<<<(N_NODES * FEAT / 4 + 255) / 256, 256, 0, stream>>>(x, xb, N_NODES * FEAT / 4);
  prep_tp<<<T1 + T2, 256, 0, stream>>>(Wq1, Wk1, Wv1, Ws1, Wq2, Wk2, Wv2, Ws2, W1t, W2t);
  bias_kernel<<<(2048 + 1664 + 255) / 256, 256, 0, stream>>>(
      bq1, bk1, bv1, bs1, bq2, bk2, bv2, bs2, Bh1, Bh2);

  // ---- CSR build ----
  zero_kernel<<<(N_NODES + 255) / 256, 256, 0, stream>>>(deg, counter, gstart, gend, pooled);
  hist_bounds_kernel<<<(EDGES + 255) / 256, 256, 0, stream>>>(dstp, deg, batch, gstart, gend);
  alloc_kernel<<<(N_NODES + 255) / 256, 256, 0, stream>>>(deg, counter, start, cursor);
  scatter_kernel<<<(EDGES + 255) / 256, 256, 0, stream>>>(srcp, dstp, cursor, csr);

  const int gx8 = 49 * 8;               // 392 row tiles (padded; kernel guards)
  const int ga = (N_NODES + 3) / 4;     // 12500

  // ---- layer 1: per head-pair, GEMM (1024 cols) + attention (fused skip+ELU) ----
  for (int p = 0; p < 2; ++p) {
    gemm_bt<<<gx8 * 8, 256, 0, stream>>>(
        xb, W1t + (size_t)p * 1024 * FEAT, Bh1 + p * 1024, BIG, 1024, N_NODES, FEAT, 8);
    attn1_kernel<<<dim3(ga, 2), 256, 0, stream>>>(BIG, start, deg, csr, H1b, p);
  }

  // ---- layer 2: pair0 GEMM includes skip cols (896, ldc=1024); attn2 writes S2 ----
  gemm_bt<<<gx8 * 7, 256, 0, stream>>>(
      H1b, W2t, Bh2, BIG, 1024, N_NODES, HID, 7);
  attn2_kernel<<<ga, 256, 0, stream>>>(BIG, start, deg, csr, S2, 1);
  gemm_bt<<<gx8 * 6, 256, 0, stream>>>(
      H1b, W2t + (size_t)896 * HID, Bh2 + 896, BIG, 1024, N_NODES, HID, 6);
  attn2_kernel<<<ga, 256, 0, stream>>>(BIG, start, deg, csr, S2, 0);

  // ---- pool (fused ELU) + classify ----
  pool_accum<<<(N_NODES * CH + 255) / 256, 256, 0, stream>>>(S2, batch, pooled);
  cls_kernel<<<NGRAPH, CH, 0, stream>>>(pooled, gstart, gend, Wfc, bfc, out);
}